// Round 15
// baseline (485.973 us; speedup 1.0000x reference)
//
#include <hip/hip_runtime.h>
#include <hip/hip_bf16.h>

// Problem constants (fixed by setup_inputs)
#define BATCH 4
#define NTOK 3137        // 1 + 56*56
#define DIM 768
#define NHEAD 12
#define HD 64
#define QH 56
#define QW 56
#define NKEY 785         // 1 + 28*28
#define NKEYPAD 800      // padded key count (25 x 32)
#define THREE_DIM 2304
#define MROWS (BATCH*NTOK)   // 12548
#define QTB 256              // attn q-rows per block (8 waves x 32)
#define NQB 13               // ceil(3137/256)
#define NBH 48               // BATCH*NHEAD
#define RELROWS (NBH*56)     // 2688
#define XD 128               // extended head dim (64 q + 28 relh + 28 relw + pad flag)

// exp2 folding: q pre-scale = 0.125 * log2(e); scores come out in log2 units
#define QSCALE 0.1803368801111204f
#define QUNSCALE 5.5451774444795625f   // 1/QSCALE (residual recovery)
#define PADSUP  -43.3f                 // -30 * log2(e)

typedef __attribute__((ext_vector_type(8))) short bf16x8;
typedef __attribute__((ext_vector_type(4))) float f32x4;

__device__ __forceinline__ unsigned short f2bf(float f) {
    union { float f; unsigned u; } v; v.f = f;
    unsigned r = v.u + 0x7FFFu + ((v.u >> 16) & 1u);   // RNE
    return (unsigned short)(r >> 16);
}
__device__ __forceinline__ float bf2f(unsigned short s) {
    union { unsigned u; float f; } v; v.u = (unsigned)s << 16; return v.f;
}

__device__ __forceinline__ void gl16(const void* g, void* l) {
    __builtin_amdgcn_global_load_lds(
        (const __attribute__((address_space(1))) unsigned int*)g,
        (__attribute__((address_space(3))) unsigned int*)l, 16, 0, 0);
}

// ---------------------------------------------------------------------------
// fp32 -> bf16 elementwise (vectorized x4)
// ---------------------------------------------------------------------------
__global__ __launch_bounds__(256) void cvt_bf16(
    const float* __restrict__ in, unsigned short* __restrict__ outp, int n4)
{
    for (int i = blockIdx.x * 256 + threadIdx.x; i < n4; i += gridDim.x * 256) {
        float4 v = reinterpret_cast<const float4*>(in)[i];
        union { unsigned short s[4]; uint2 u; } o;
        o.s[0] = f2bf(v.x); o.s[1] = f2bf(v.y);
        o.s[2] = f2bf(v.z); o.s[3] = f2bf(v.w);
        reinterpret_cast<uint2*>(outp)[i] = o.u;
    }
}

// Both rel tables in one launch (n4 = 1776 each)
__global__ __launch_bounds__(256) void cvt_rel(
    const float* __restrict__ h, const float* __restrict__ w,
    unsigned short* __restrict__ hb, unsigned short* __restrict__ wb)
{
    int i = blockIdx.x * 256 + threadIdx.x;
    const float* src; unsigned short* dst; int j;
    if (i < 1776)      { src = h; dst = hb; j = i; }
    else if (i < 3552) { src = w; dst = wb; j = i - 1776; }
    else return;
    float4 v = reinterpret_cast<const float4*>(src)[j];
    union { unsigned short s[4]; uint2 u; } o;
    o.s[0] = f2bf(v.x); o.s[1] = f2bf(v.y);
    o.s[2] = f2bf(v.z); o.s[3] = f2bf(v.w);
    reinterpret_cast<uint2*>(dst)[j] = o.u;
}

// ---------------------------------------------------------------------------
// W[K][N] fp32 -> Wt[N][K] bf16; z=0: Wqkv(768x2304), z=1: Wproj(768x768)
// ---------------------------------------------------------------------------
__global__ __launch_bounds__(256) void transpose_bf16_2(
    const float* __restrict__ W0, unsigned short* __restrict__ Wt0,
    const float* __restrict__ W1, unsigned short* __restrict__ Wt1)
{
    const float* W; unsigned short* Wt; int N;
    if (blockIdx.z == 0) { W = W0; Wt = Wt0; N = THREE_DIM; }
    else {
        if (blockIdx.x >= DIM / 32) return;
        W = W1; Wt = Wt1; N = DIM;
    }
    const int K = DIM;
    __shared__ float tile[32][33];
    int k0 = blockIdx.y * 32, n0 = blockIdx.x * 32;
    int t = threadIdx.x;
    int r = t >> 5, c = t & 31;
    #pragma unroll
    for (int p = 0; p < 4; ++p)
        tile[r + p * 8][c] = W[(size_t)(k0 + r + p * 8) * N + n0 + c];
    __syncthreads();
    #pragma unroll
    for (int p = 0; p < 4; ++p)
        Wt[(size_t)(n0 + r + p * 8) * K + k0 + c] = f2bf(tile[c][r + p * 8]);
}

// ---------------------------------------------------------------------------
// bf16 MFMA GEMM, 128x128 tile, 4 waves (2x2), BK=32, 3-stage LDS pipeline
// (48 KB), counted vmcnt(4), ONE top barrier per iter. setprio around MFMA.
// ---------------------------------------------------------------------------
__global__ __launch_bounds__(256, 3) void gemm_mfma(
    const unsigned short* __restrict__ A, const unsigned short* __restrict__ Bt,
    const float* __restrict__ bias, void* __restrict__ C,
    int M, int N, int K, int out_bf16)
{
    __shared__ __align__(16) char lds[49152];   // 3 stages x (A 8K | B 8K)
    int t = threadIdx.x;
    int wave = t >> 6, lane = t & 63;
    int lm = lane & 15, lkg = lane >> 4;
    int wr = wave >> 1, wc = wave & 1;

    // bijective XCD remap (m204)
    int gx = gridDim.x;
    int nwg = gx * gridDim.y;
    int lin = blockIdx.y * gx + blockIdx.x;
    int qq = nwg >> 3, rr = nwg & 7;
    int xcd = lin & 7, idx = lin >> 3;
    int newlin = (xcd < rr ? xcd * (qq + 1) : rr * (qq + 1) + (xcd - rr) * qq) + idx;
    int m0 = (newlin / gx) * 128, n0 = (newlin % gx) * 128;

    // staging roles: 2 chunks per matrix per thread, pre-swizzled source
    const unsigned short *gpa0, *gpa1, *gpb0, *gpb1;
    int la0, la1, lb0, lb1;
    {
        int o0 = t * 16, o1 = 4096 + t * 16;
        int r0 = o0 >> 6, s0 = ((o0 >> 4) & 3) ^ ((r0 >> 1) & 3);
        int r1 = o1 >> 6, s1 = ((o1 >> 4) & 3) ^ ((r1 >> 1) & 3);
        int ar0 = m0 + r0; if (ar0 >= M) ar0 = M - 1;
        int ar1 = m0 + r1; if (ar1 >= M) ar1 = M - 1;
        gpa0 = A + (size_t)ar0 * K + s0 * 8;  la0 = o0;
        gpa1 = A + (size_t)ar1 * K + s1 * 8;  la1 = o1;
        gpb0 = Bt + (size_t)(n0 + r0) * K + s0 * 8;  lb0 = 8192 + o0;
        gpb1 = Bt + (size_t)(n0 + r1) * K + s1 * 8;  lb1 = 8192 + o1;
    }

    f32x4 acc[4][4] = {};
    const int nt = K >> 5;      // 24

    // prologue: stage tiles 0 (buf0) and 1 (buf1); 8 loads stay in flight
    gl16(gpa0, &lds[la0]); gl16(gpa1, &lds[la1]);
    gl16(gpb0, &lds[lb0]); gl16(gpb1, &lds[lb1]);
    gpa0 += 32; gpa1 += 32; gpb0 += 32; gpb1 += 32;
    gl16(gpa0, &lds[16384 + la0]); gl16(gpa1, &lds[16384 + la1]);
    gl16(gpb0, &lds[16384 + lb0]); gl16(gpb1, &lds[16384 + lb1]);
    gpa0 += 32; gpa1 += 32; gpb0 += 32; gpb1 += 32;

    int cur = 0;
    for (int tt = 0; tt < nt; ++tt) {
        if (tt + 1 < nt) asm volatile("s_waitcnt vmcnt(4)" ::: "memory");
        else             asm volatile("s_waitcnt vmcnt(0)" ::: "memory");
        __builtin_amdgcn_s_barrier();   // tile tt fully in LDS (all waves)

        // stage tile tt+2 -> buf[(cur+2)%3] (its readers retired at tt-1)
        if (tt + 2 < nt) {
            int nx = cur + 2; if (nx >= 3) nx -= 3;
            char* nb = &lds[nx << 14];
            gl16(gpa0, nb + la0); gl16(gpa1, nb + la1);
            gl16(gpb0, nb + lb0); gl16(gpb1, nb + lb1);
            gpa0 += 32; gpa1 += 32; gpb0 += 32; gpb1 += 32;
        }

        char* base = &lds[cur << 14];
        bf16x8 af[4], bfr[4];
        #pragma unroll
        for (int m = 0; m < 4; ++m) {
            int row = wr * 64 + m * 16 + lm;
            af[m] = *reinterpret_cast<const bf16x8*>(
                base + row * 64 + ((lkg ^ ((row >> 1) & 3)) << 4));
        }
        #pragma unroll
        for (int n = 0; n < 4; ++n) {
            int row = wc * 64 + n * 16 + lm;
            bfr[n] = *reinterpret_cast<const bf16x8*>(
                base + 8192 + row * 64 + ((lkg ^ ((row >> 1) & 3)) << 4));
        }
        __builtin_amdgcn_s_setprio(1);
        #pragma unroll
        for (int m = 0; m < 4; ++m)
            #pragma unroll
            for (int n = 0; n < 4; ++n)
                acc[m][n] = __builtin_amdgcn_mfma_f32_16x16x32_bf16(
                    af[m], bfr[n], acc[m][n], 0, 0, 0);
        __builtin_amdgcn_s_setprio(0);

        cur = (cur == 2) ? 0 : cur + 1;
    }

    // epilogue: row-contiguous store order (n innermost => full 128B lines)
    float bv[4];
    #pragma unroll
    for (int n = 0; n < 4; ++n)
        bv[n] = bias ? bias[n0 + wc * 64 + n * 16 + lm] : 0.f;
    #pragma unroll
    for (int m = 0; m < 4; ++m) {
        #pragma unroll
        for (int r = 0; r < 4; ++r) {
            int row = m0 + wr * 64 + m * 16 + lkg * 4 + r;
            if (row >= M) continue;
            #pragma unroll
            for (int n = 0; n < 4; ++n) {
                int col = n0 + wc * 64 + n * 16 + lm;
                float o = acc[m][n][r] + bv[n];
                if (out_bf16)
                    ((unsigned short*)C)[(size_t)row * N + col] = f2bf(o);
                else
                    ((float*)C)[(size_t)row * N + col] = o;
            }
        }
    }
}

// ---------------------------------------------------------------------------
// Row-tiled depthwise 3x3 pool + LayerNorm (shared body).
// mode 3: q-ext [bh][pos][128] (q*QSCALE, ext zeros, [120]=PADSUP)
// mode 1: k-ext [bh][pos][128] (k, onehot(kh)/onehot(kw))
// mode 2: v^T   [bh][64][NKEYPAD]
// ---------------------------------------------------------------------------
__device__ __forceinline__ void pool_body(
    const unsigned short* src, const float* w, const float* g,
    const float* beta, unsigned short* outp, int bh, int orow,
    int stride, int OW, int mode, unsigned short* ibuf,
    int t, int wave, int lane)
{
    for (int i = t; i < 3 * 56 * 32; i += 256) {
        int pair = i >> 5, off = i & 31;
        int r = pair / 56, iw = pair % 56;
        int ih = orow * stride + r - 1;
        unsigned v = 0;
        if (ih >= 0 && ih < QH)
            v = *reinterpret_cast<const unsigned*>(
                src + (size_t)(1 + ih * QW + iw) * THREE_DIM + off * 2);
        *reinterpret_cast<unsigned*>(&ibuf[pair * 64 + off * 2]) = v;
    }

    float wreg[9];
    #pragma unroll
    for (int k = 0; k < 9; ++k) wreg[k] = w[lane * 9 + k];
    float gl = g[lane], bl = beta[lane];
    __syncthreads();

    int ntask = OW + ((orow == 0) ? 1 : 0);    // extra task: cls (pos 0)
    for (int task = wave; task < ntask; task += 4) {
        float val;
        int pos;
        if (task == OW) {                      // cls token
            val = bf2f(src[lane]);
            pos = 0;
        } else {
            int ow = task;
            float acc = 0.f;
            #pragma unroll
            for (int r = 0; r < 3; ++r) {
                #pragma unroll
                for (int c = 0; c < 3; ++c) {
                    int iwc = ow * stride + c - 1;
                    if (iwc < 0 || iwc >= QW) continue;
                    acc += bf2f(ibuf[(r * 56 + iwc) * 64 + lane]) * wreg[r * 3 + c];
                }
            }
            val = acc;
            pos = 1 + orow * OW + ow;
        }

        float mu = val;
        #pragma unroll
        for (int off = 32; off > 0; off >>= 1) mu += __shfl_xor(mu, off, 64);
        mu *= (1.f / 64.f);
        float dv = val - mu;
        float var = dv * dv;
        #pragma unroll
        for (int off = 32; off > 0; off >>= 1) var += __shfl_xor(var, off, 64);
        var *= (1.f / 64.f);
        float o = dv * rsqrtf(var + 1e-5f) * gl + bl;

        if (mode == 3) {
            unsigned short* row = outp + ((size_t)bh * NTOK + pos) * XD;
            row[lane] = f2bf(o * QSCALE);
            row[64 + lane] = (lane == 56) ? f2bf(PADSUP) : 0;
        } else if (mode == 1) {
            unsigned short* row = outp + ((size_t)bh * NKEYPAD + pos) * XD;
            row[lane] = f2bf(o);
            unsigned short ext = 0;
            if (pos > 0) {
                int kh = (pos - 1) / 28, kw = (pos - 1) % 28;
                if ((lane < 28 && lane == kh) ||
                    (lane >= 28 && lane < 56 && lane - 28 == kw))
                    ext = 0x3F80;   // 1.0 bf16
            }
            row[64 + lane] = ext;
        } else {
            outp[((size_t)bh * HD + lane) * NKEYPAD + pos] = f2bf(o);
        }
    }
}

__global__ __launch_bounds__(256) void pool_ln_q(
    const unsigned short* __restrict__ qkvb, const float* __restrict__ w,
    const float* __restrict__ g, const float* __restrict__ beta,
    unsigned short* __restrict__ outp)
{
    __shared__ unsigned short ibuf[3 * 56 * 64];
    int bid = blockIdx.x;
    int orow = bid % QH;
    int bh = bid / QH;
    int head = bh % NHEAD, b = bh / NHEAD;
    const unsigned short* src =
        qkvb + (size_t)b * NTOK * THREE_DIM + (size_t)head * HD;
    pool_body(src, w, g, beta, outp, bh, orow, 1, QW, 3, ibuf,
              threadIdx.x, threadIdx.x >> 6, threadIdx.x & 63);
}

// k (y=0) and v (y=1) pools in one launch
__global__ __launch_bounds__(256) void pool_ln_kv(
    const unsigned short* __restrict__ qkvb,
    const float* __restrict__ wk, const float* __restrict__ gk,
    const float* __restrict__ bk, unsigned short* __restrict__ kpx,
    const float* __restrict__ wv, const float* __restrict__ gv,
    const float* __restrict__ bv, unsigned short* __restrict__ vt16)
{
    __shared__ unsigned short ibuf[3 * 56 * 64];
    int bid = blockIdx.x;
    int orow = bid % 28;
    int bh = bid / 28;
    int head = bh % NHEAD, b = bh / NHEAD;
    int isv = blockIdx.y;
    const unsigned short* src = qkvb + (size_t)b * NTOK * THREE_DIM
        + (size_t)(isv ? 2 : 1) * DIM + (size_t)head * HD;
    if (isv)
        pool_body(src, wv, gv, bv, vt16, bh, orow, 2, 28, 2, ibuf,
                  threadIdx.x, threadIdx.x >> 6, threadIdx.x & 63);
    else
        pool_body(src, wk, gk, bk, kpx, bh, orow, 2, 28, 1, ibuf,
                  threadIdx.x, threadIdx.x >> 6, threadIdx.x & 63);
}

// ---------------------------------------------------------------------------
// Pad rows (785..799): k-ext rows = pad-flag onehot; v^T pad cols = 0.
// ---------------------------------------------------------------------------
__global__ __launch_bounds__(64) void pad_kv(
    unsigned short* __restrict__ kpx, unsigned short* __restrict__ vt16)
{
    int bh = blockIdx.x;
    int t = threadIdx.x;
    for (int pos = NKEY; pos < NKEYPAD; ++pos) {
        unsigned short* row = kpx + ((size_t)bh * NKEYPAD + pos) * XD;
        row[t] = 0;
        row[64 + t] = (t == 56) ? 0x3F80 : 0;
        vt16[((size_t)bh * HD + t) * NKEYPAD + pos] = 0;
    }
}

// ---------------------------------------------------------------------------
// MFMA rel-pos dots -> bf16 Q-ext columns of qpx. blockIdx.z = mode.
// ---------------------------------------------------------------------------
__global__ __launch_bounds__(256) void rel_mfma(
    const unsigned short* __restrict__ qpx, const unsigned short* __restrict__ rh,
    const unsigned short* __restrict__ rw, unsigned short* __restrict__ qpx_out)
{
    __shared__ char bbuf[4096];     // [32 rows][64 bf16], XOR-swizzled
    int X = blockIdx.x;
    int m0 = blockIdx.y * 256;
    int mode = blockIdx.z;
    const unsigned short* rtab = mode ? rw : rh;
    int t = threadIdx.x;
    int wave = t >> 6, lane = t & 63;
    int lm = lane & 15, lkg = lane >> 4;

    {
        int row = t >> 3, c8 = t & 7;
        int4 val = {0, 0, 0, 0};
        if (row < 28) {
            int dh = X - 2 * row + 54;              // in [0, 110)
            val = *reinterpret_cast<const int4*>(rtab + (size_t)dh * HD + c8 * 8);
        }
        *reinterpret_cast<int4*>(&bbuf[row * 128 + ((c8 * 16) ^ ((row & 7) << 4))]) = val;
    }
    __syncthreads();

    int rbase = m0 + wave * 64 + lm;
    f32x4 acc[4][2] = {};
    #pragma unroll
    for (int kc = 0; kc < 2; ++kc) {
        bf16x8 bfrag[2];
        #pragma unroll
        for (int nb = 0; nb < 2; ++nb) {
            int row = nb * 16 + lm;
            bfrag[nb] = *reinterpret_cast<const bf16x8*>(
                &bbuf[row * 128 + (((kc * 4 + lkg) * 16) ^ ((row & 7) << 4))]);
        }
        #pragma unroll
        for (int m = 0; m < 4; ++m) {
            int rho = rbase + m * 16; if (rho > RELROWS - 1) rho = RELROWS - 1;
            int bh = rho / 56, rem = rho % 56;
            int pos1 = (mode == 0) ? X * 56 + rem : rem * 56 + X;
            const unsigned short* qsrc =
                qpx + ((size_t)bh * NTOK + 1 + pos1) * XD + kc * 32 + lkg * 8;
            bf16x8 af = *reinterpret_cast<const bf16x8*>(qsrc);
            acc[m][0] = __builtin_amdgcn_mfma_f32_16x16x32_bf16(af, bfrag[0], acc[m][0], 0, 0, 0);
            acc[m][1] = __builtin_amdgcn_mfma_f32_16x16x32_bf16(af, bfrag[1], acc[m][1], 0, 0, 0);
        }
    }

    #pragma unroll
    for (int m = 0; m < 4; ++m) {
        #pragma unroll
        for (int r = 0; r < 4; ++r) {
            int rho = m0 + wave * 64 + m * 16 + lkg * 4 + r;
            if (rho >= RELROWS) continue;
            int bh = rho / 56, rem = rho % 56;
            int pos1 = (mode == 0) ? X * 56 + rem : rem * 56 + X;
            unsigned short* dst =
                qpx_out + ((size_t)bh * NTOK + 1 + pos1) * XD + 64 + mode * 28;
            dst[lm] = f2bf(acc[m][0][r] * 8.f);             // -> log2e * (q.r)
            if (lm < 12) dst[16 + lm] = f2bf(acc[m][1][r] * 8.f);
        }
    }
}

// ---------------------------------------------------------------------------
// MFMA flash attention, 8 waves x 32 q-rows (QT=256, 512 thr), swapped QK
// (mfma(K,Q): lane holds q=lm, keys lkg*4+r), bias in ext-128 K-dim, 3-stage
// pipeline (counted vmcnt(2), ONE barrier/iter), XCD swizzle, exp2 scores.
// Per-wave structure identical to the verified r13 kernel; staging/barriers
// amortized over 8 waves; grid 624 blocks -> single round (3 blocks/CU).
// K staging: 1 chunk/thread (512x16B = 8KB exact). V staging: duplicate-
// write trick (vidx = t&255; waves 4-7 rewrite same bytes) so the
// global_load_lds wave-uniform-base semantics hold and all waves issue a
// uniform 2 loads/tile (counted-vmcnt correctness).
// osum partials reduced over lkg groups (shfl_xor 16/32) before reciprocal.
// ---------------------------------------------------------------------------
__global__ __launch_bounds__(512, 6) void attn_mfma(
    const unsigned short* __restrict__ qpx, const unsigned short* __restrict__ kpx,
    const unsigned short* __restrict__ vt, unsigned short* __restrict__ outp)
{
    __shared__ __align__(16) char kbuf[3][8192];   // Kext tile [32][128] bf16
    __shared__ __align__(16) char vbuf[3][4096];   // Vt tile  [64][32]  bf16
    __shared__ __align__(16) char pbuf[8][2048];   // per-wave P [32 q][32 k]

    int bid0 = blockIdx.x;
    int bid = (bid0 & 7) * ((NBH * NQB) / 8) + (bid0 >> 3);   // 624 % 8 == 0
    int tile = bid % NQB;
    int bh = bid / NQB;
    int head = bh % NHEAD, b = bh / NHEAD;
    int q0 = tile * QTB;
    int t = threadIdx.x;
    int wave = t >> 6, lane = t & 63;
    int lm = lane & 15, lkg = lane >> 4;

    const unsigned short* kb  = kpx + (size_t)bh * NKEYPAD * XD;
    const unsigned short* vtb = vt + (size_t)bh * HD * NKEYPAD;

    // Q fragments: 2 row-blocks x 4 chunks of 32 ext-dims (wave owns 32 rows)
    bf16x8 qf[2][4] = {};
    #pragma unroll
    for (int rb = 0; rb < 2; ++rb) {
        int qrow = q0 + wave * 32 + rb * 16 + lm;
        if (qrow < NTOK) {
            const unsigned short* qs = qpx + ((size_t)bh * NTOK + qrow) * XD + lkg * 8;
            qf[rb][0] = *reinterpret_cast<const bf16x8*>(qs);
            qf[rb][1] = *reinterpret_cast<const bf16x8*>(qs + 32);
            qf[rb][2] = *reinterpret_cast<const bf16x8*>(qs + 64);
            qf[rb][3] = *reinterpret_cast<const bf16x8*>(qs + 96);
        }
    }

    f32x4 oacc[2][4] = {};
    float osum[2] = {0.f, 0.f};    // partial per lane: q = lm, keys of lkg grp

    // K staging: 1 chunk/thread, 512 x 16B = 8KB tile exactly.
    int kr = t >> 4;                 // rows 0..31
    int ks = (t & 15) ^ (kr & 7);    // pre-swizzled source slot
    const unsigned short* kp0 = kb + (size_t)kr * XD + ks * 8;
    int kd = t * 16;
    // V staging: duplicate across wave-halves (vidx = t & 255).
    int vidx = t & 255;
    int vr = vidx >> 2;
    int vs = (vidx & 3) ^ ((vr >> 1) & 3);
    const unsigned short* vp0 = vtb + (size_t)vr * NKEYPAD + vs * 8;
    int vd = vidx * 16;              // = (wave&3)*1024 + lane*16 (uniform base)

    const int NT = NKEYPAD / 32;   // 25

    // prologue: stage tiles 0,1 (2 loads per thread per tile)
    gl16(kp0, &kbuf[0][kd]); gl16(vp0, &vbuf[0][vd]);
    kp0 += 32 * XD; vp0 += 32;
    gl16(kp0, &kbuf[1][kd]); gl16(vp0, &vbuf[1][vd]);
    kp0 += 32 * XD; vp0 += 32;

    // P write address base: byte(P[q][k]) = (k>>3)*256 + q*16 + (k&7)*2
    int pwbase = lm * 16 + ((lkg & 1) << 3);   // + (nb*2 + (lkg>>1))*256 + rb*1024

    int cur = 0;
    for (int jt = 0; jt < NT; ++jt) {
        if (jt + 1 < NT) asm volatile("s_waitcnt vmcnt(2)" ::: "memory");
        else             asm volatile("s_waitcnt vmcnt(0)" ::: "memory");
        __builtin_amdgcn_s_barrier();   // tile jt fully in LDS

        // stage tile jt+2 into buf[(jt+2)%3] (last read at jt-1, retired)
        if (jt + 2 < NT) {
            int nx = cur + 2; if (nx >= 3) nx -= 3;
            gl16(kp0, &kbuf[nx][kd]);
            gl16(vp0, &vbuf[nx][vd]);
            kp0 += 32 * XD; vp0 += 32;
        }

        // Swapped QK^T: S[k][q] = mfma(Kext, Qext); kf shared across both rb
        f32x4 a00 = {0.f,0.f,0.f,0.f}, a01 = {0.f,0.f,0.f,0.f};
        f32x4 a10 = {0.f,0.f,0.f,0.f}, a11 = {0.f,0.f,0.f,0.f};
        __builtin_amdgcn_s_setprio(1);
        #pragma unroll
        for (int kc = 0; kc < 4; ++kc) {
            int sl = (kc * 4 + lkg) ^ (lm & 7);
            bf16x8 kf0 = *reinterpret_cast<const bf16x8*>(&kbuf[cur][lm * 256 + sl * 16]);
            bf16x8 kf1 = *reinterpret_cast<const bf16x8*>(&kbuf[cur][(16 + lm) * 256 + sl * 16]);
            a00 = __builtin_amdgcn_mfma_f32_16x16x32_bf16(kf0, qf[0][kc], a00, 0, 0, 0);
            a01 = __builtin_amdgcn_mfma_f32_16x16x32_bf16(kf1, qf[0][kc], a01, 0, 0, 0);
            a10 = __builtin_amdgcn_mfma_f32_16x16x32_bf16(kf0, qf[1][kc], a10, 0, 0, 0);
            a11 = __builtin_amdgcn_mfma_f32_16x16x32_bf16(kf1, qf[1][kc], a11, 0, 0, 0);
        }
        __builtin_amdgcn_s_setprio(0);

        // exp2 + pack pairs + b64 write (4 consecutive k per write)
        #pragma unroll
        for (int rb = 0; rb < 2; ++rb) {
            #pragma unroll
            for (int nb = 0; nb < 2; ++nb) {
                f32x4 a = rb ? (nb ? a11 : a10) : (nb ? a01 : a00);
                float e0, e1, e2, e3;
                asm("v_exp_f32 %0, %1" : "=v"(e0) : "v"(a[0]));
                asm("v_exp_f32 %0, %1" : "=v"(e1) : "v"(a[1]));
                asm("v_exp_f32 %0, %1" : "=v"(e2) : "v"(a[2]));
                asm("v_exp_f32 %0, %1" : "=v"(e3) : "v"(a[3]));
                osum[rb] += (e0 + e1) + (e2 + e3);
                union { float f; unsigned u; } u0, u1, u2, u3;
                u0.f = e0; u1.f = e1; u2.f = e2; u3.f = e3;
                uint2 pk;
                pk.x = (u0.u >> 16) | (u1.u & 0xFFFF0000u);   // k+0, k+1
                pk.y = (u2.u >> 16) | (u3.u & 0xFFFF0000u);   // k+2, k+3
                int addr = (rb << 10) + ((nb * 2 + (lkg >> 1)) << 8) + pwbase;
                *reinterpret_cast<uint2*>(&pbuf[wave][addr]) = pk;
            }
        }

        // PV: O[rb] += P[rb][16x32] * Vt ; pf read is lane-linear (no conflict)
        bf16x8 pf0 = *reinterpret_cast<const bf16x8*>(&pbuf[wave][lane * 16]);
        bf16x8 pf1 = *reinterpret_cast<const bf16x8*>(&pbuf[wave][1024 + lane * 16]);
        __builtin_amdgcn_s_setprio(1);
        #pragma unroll
        for (int db = 0; db < 4; ++db) {
            int row = db * 16 + lm;
            bf16x8 vf = *reinterpret_cast<const bf16x8*>(
                &vbuf[cur][row * 64 + ((lkg ^ ((row >> 1) & 3)) << 4)]);
            oacc[0][db] = __builtin_amdgcn_mfma_f32_16x16x32_bf16(pf0, vf, oacc[0][db], 0, 0, 0);
            oacc[1][db] = __builtin_amdgcn_mfma_f32_16x16x32_bf16(pf1, vf, oacc[1][db], 0, 0, 0);
        }
        __builtin_amdgcn_s_setprio(0);

        cur = (cur == 2) ? 0 : cur + 1;
    }

    // FULL denominator: reduce partials across the 4 lkg groups (bits 4,5),
    // then lane-local reciprocal; broadcast to output layout via shfl.
    #pragma unroll
    for (int rb = 0; rb < 2; ++rb) {
        osum[rb] += __shfl_xor(osum[rb], 16, 64);
        osum[rb] += __shfl_xor(osum[rb], 32, 64);
    }
    float inv[2] = { 1.f / osum[0], 1.f / osum[1] };
    #pragma unroll
    for (int rb = 0; rb < 2; ++rb) {
        #pragma unroll
        for (int r = 0; r < 4; ++r) {
            float invq = __shfl(inv[rb], lkg * 4 + r, 64);   // lane with lm = q
            int qpos = q0 + wave * 32 + rb * 16 + lkg * 4 + r;
            if (qpos >= NTOK) continue;
            unsigned short* orow = outp + ((size_t)b * NTOK + qpos) * DIM + (size_t)head * HD;
            const unsigned short* qres = qpx + ((size_t)bh * NTOK + qpos) * XD;
            #pragma unroll
            for (int db = 0; db < 4; ++db) {
                int d = db * 16 + lm;
                float o = oacc[rb][db][r] * invq;
                if (qpos > 0) o += bf2f(qres[d]) * QUNSCALE;   // residual
                orow[d] = f2bf(o);
            }
        }
    }
}

// ---------------------------------------------------------------------------
extern "C" void kernel_launch(void* const* d_in, const int* in_sizes, int n_in,
                              void* d_out, int out_size, void* d_ws, size_t ws_size,
                              hipStream_t stream) {
    const float* x     = (const float*)d_in[0];
    const float* Wqkv  = (const float*)d_in[1];
    const float* pqw   = (const float*)d_in[2];
    const float* pkw   = (const float*)d_in[3];
    const float* pvw   = (const float*)d_in[4];
    const float* gq    = (const float*)d_in[5];
    const float* bq    = (const float*)d_in[6];
    const float* gk    = (const float*)d_in[7];
    const float* bk    = (const float*)d_in[8];
    const float* gv    = (const float*)d_in[9];
    const float* bv    = (const float*)d_in[10];
    const float* rph   = (const float*)d_in[11];
    const float* rpw   = (const float*)d_in[12];
    const float* Wproj = (const float*)d_in[13];
    const float* bproj = (const float*)d_in[14];

    unsigned short* qkvb  = (unsigned short*)d_ws;                 // [M][2304] bf16
    unsigned short* qpx   = qkvb + (size_t)MROWS * THREE_DIM;      // [48][3137][128]
    unsigned short* kpx   = qpx + (size_t)NBH * NTOK * XD;         // [48][800][128]
    unsigned short* vt16  = kpx + (size_t)NBH * NKEYPAD * XD;      // [48][64][800]
    unsigned short* xbf   = vt16 + (size_t)NBH * HD * NKEYPAD;     // [M][768]
    unsigned short* wqkvt = xbf + (size_t)MROWS * DIM;             // [2304][768]
    unsigned short* wprojt= wqkvt + (size_t)DIM * THREE_DIM;       // [768][768]
    unsigned short* rphb  = wprojt + (size_t)DIM * DIM;            // [111][64]
    unsigned short* rpwb  = rphb + 7104;
    unsigned short* attn_bf = qkvb;            // alias (qkvb dead after pools)

    dim3 blk(256);

    // 0) bf16 conversions (consolidated)
    cvt_bf16<<<2048, blk, 0, stream>>>(x, xbf, (int)((size_t)MROWS * DIM / 4));
    {
        dim3 g(THREE_DIM / 32, DIM / 32, 2);
        transpose_bf16_2<<<g, blk, 0, stream>>>(Wqkv, wqkvt, Wproj, wprojt);
    }
    cvt_rel<<<14, blk, 0, stream>>>(rph, rpw, rphb, rpwb);

    // 1) qkv = x @ Wqkv   (bf16 MFMA 128^2 pipelined, bf16 out)
    {
        dim3 grid(THREE_DIM / 128, (MROWS + 127) / 128);
        gemm_mfma<<<grid, blk, 0, stream>>>(xbf, wqkvt, nullptr, qkvb,
                                            MROWS, THREE_DIM, DIM, 1);
    }

    // 2) pool + LN: q-ext; k-ext + v^T merged; then pad rows
    pool_ln_q<<<NBH * QH, blk, 0, stream>>>(qkvb, pqw, gq, bq, qpx);
    {
        dim3 g(NBH * 28, 2);
        pool_ln_kv<<<g, blk, 0, stream>>>(qkvb, pkw, gk, bk, kpx,
                                          pvw, gv, bv, vt16);
    }
    pad_kv<<<NBH, 64, 0, stream>>>(kpx, vt16);

    // 3) rel-pos dots -> Q-ext columns (bf16, in-place into qpx), both modes
    {
        dim3 g(56, (RELROWS + 255) / 256, 2);
        rel_mfma<<<g, blk, 0, stream>>>(qpx, rphb, rpwb, qpx);
    }

    // 4) MFMA flash attention (bias folded, exp2 scores, 8 waves/block)
    attn_mfma<<<NBH * NQB, 512, 0, stream>>>(qpx, kpx, vt16, attn_bf);

    // 5) out = attn_out @ Wproj + bproj   (bf16 MFMA, fp32 out)
    {
        dim3 grid(DIM / 128, (MROWS + 127) / 128);
        gemm_mfma<<<grid, blk, 0, stream>>>(attn_bf, wprojt, bproj, d_out,
                                            MROWS, DIM, DIM, 0);
    }
}

// Round 16
// 280.934 us; speedup vs baseline: 1.7298x; 1.7298x over previous
//
#include <hip/hip_runtime.h>
#include <hip/hip_bf16.h>

// Problem constants (fixed by setup_inputs)
#define BATCH 4
#define NTOK 3137        // 1 + 56*56
#define DIM 768
#define NHEAD 12
#define HD 64
#define QH 56
#define QW 56
#define NKEY 785         // 1 + 28*28
#define NKEYPAD 800      // padded key count (25 x 32)
#define THREE_DIM 2304
#define MROWS (BATCH*NTOK)   // 12548
#define QTB 256              // attn q-rows per block (8 waves x 32)
#define NQB 13               // ceil(3137/256)
#define NBH 48               // BATCH*NHEAD
#define RELROWS (NBH*56)     // 2688
#define XD 128               // extended head dim (64 q + 28 relh + 28 relw + pad flag)

// exp2 folding: q pre-scale = 0.125 * log2(e); scores come out in log2 units
#define QSCALE 0.1803368801111204f
#define QUNSCALE 5.5451774444795625f   // 1/QSCALE (residual recovery)
#define PADSUP  -43.3f                 // -30 * log2(e)

typedef __attribute__((ext_vector_type(8))) short bf16x8;
typedef __attribute__((ext_vector_type(4))) float f32x4;

__device__ __forceinline__ unsigned short f2bf(float f) {
    union { float f; unsigned u; } v; v.f = f;
    unsigned r = v.u + 0x7FFFu + ((v.u >> 16) & 1u);   // RNE
    return (unsigned short)(r >> 16);
}
__device__ __forceinline__ float bf2f(unsigned short s) {
    union { unsigned u; float f; } v; v.u = (unsigned)s << 16; return v.f;
}

__device__ __forceinline__ void gl16(const void* g, void* l) {
    __builtin_amdgcn_global_load_lds(
        (const __attribute__((address_space(1))) unsigned int*)g,
        (__attribute__((address_space(3))) unsigned int*)l, 16, 0, 0);
}

// ---------------------------------------------------------------------------
// fp32 -> bf16 elementwise (vectorized x4)
// ---------------------------------------------------------------------------
__global__ __launch_bounds__(256) void cvt_bf16(
    const float* __restrict__ in, unsigned short* __restrict__ outp, int n4)
{
    for (int i = blockIdx.x * 256 + threadIdx.x; i < n4; i += gridDim.x * 256) {
        float4 v = reinterpret_cast<const float4*>(in)[i];
        union { unsigned short s[4]; uint2 u; } o;
        o.s[0] = f2bf(v.x); o.s[1] = f2bf(v.y);
        o.s[2] = f2bf(v.z); o.s[3] = f2bf(v.w);
        reinterpret_cast<uint2*>(outp)[i] = o.u;
    }
}

// Both rel tables in one launch (n4 = 1776 each)
__global__ __launch_bounds__(256) void cvt_rel(
    const float* __restrict__ h, const float* __restrict__ w,
    unsigned short* __restrict__ hb, unsigned short* __restrict__ wb)
{
    int i = blockIdx.x * 256 + threadIdx.x;
    const float* src; unsigned short* dst; int j;
    if (i < 1776)      { src = h; dst = hb; j = i; }
    else if (i < 3552) { src = w; dst = wb; j = i - 1776; }
    else return;
    float4 v = reinterpret_cast<const float4*>(src)[j];
    union { unsigned short s[4]; uint2 u; } o;
    o.s[0] = f2bf(v.x); o.s[1] = f2bf(v.y);
    o.s[2] = f2bf(v.z); o.s[3] = f2bf(v.w);
    reinterpret_cast<uint2*>(dst)[j] = o.u;
}

// ---------------------------------------------------------------------------
// W[K][N] fp32 -> Wt[N][K] bf16; z=0: Wqkv(768x2304), z=1: Wproj(768x768)
// ---------------------------------------------------------------------------
__global__ __launch_bounds__(256) void transpose_bf16_2(
    const float* __restrict__ W0, unsigned short* __restrict__ Wt0,
    const float* __restrict__ W1, unsigned short* __restrict__ Wt1)
{
    const float* W; unsigned short* Wt; int N;
    if (blockIdx.z == 0) { W = W0; Wt = Wt0; N = THREE_DIM; }
    else {
        if (blockIdx.x >= DIM / 32) return;
        W = W1; Wt = Wt1; N = DIM;
    }
    const int K = DIM;
    __shared__ float tile[32][33];
    int k0 = blockIdx.y * 32, n0 = blockIdx.x * 32;
    int t = threadIdx.x;
    int r = t >> 5, c = t & 31;
    #pragma unroll
    for (int p = 0; p < 4; ++p)
        tile[r + p * 8][c] = W[(size_t)(k0 + r + p * 8) * N + n0 + c];
    __syncthreads();
    #pragma unroll
    for (int p = 0; p < 4; ++p)
        Wt[(size_t)(n0 + r + p * 8) * K + k0 + c] = f2bf(tile[c][r + p * 8]);
}

// ---------------------------------------------------------------------------
// bf16 MFMA GEMM, 128x128 tile, 4 waves (2x2), BK=32, 3-stage LDS pipeline
// (48 KB), counted vmcnt(4), ONE top barrier per iter. setprio around MFMA.
// ---------------------------------------------------------------------------
__global__ __launch_bounds__(256, 3) void gemm_mfma(
    const unsigned short* __restrict__ A, const unsigned short* __restrict__ Bt,
    const float* __restrict__ bias, void* __restrict__ C,
    int M, int N, int K, int out_bf16)
{
    __shared__ __align__(16) char lds[49152];   // 3 stages x (A 8K | B 8K)
    int t = threadIdx.x;
    int wave = t >> 6, lane = t & 63;
    int lm = lane & 15, lkg = lane >> 4;
    int wr = wave >> 1, wc = wave & 1;

    // bijective XCD remap (m204)
    int gx = gridDim.x;
    int nwg = gx * gridDim.y;
    int lin = blockIdx.y * gx + blockIdx.x;
    int qq = nwg >> 3, rr = nwg & 7;
    int xcd = lin & 7, idx = lin >> 3;
    int newlin = (xcd < rr ? xcd * (qq + 1) : rr * (qq + 1) + (xcd - rr) * qq) + idx;
    int m0 = (newlin / gx) * 128, n0 = (newlin % gx) * 128;

    // staging roles: 2 chunks per matrix per thread, pre-swizzled source
    const unsigned short *gpa0, *gpa1, *gpb0, *gpb1;
    int la0, la1, lb0, lb1;
    {
        int o0 = t * 16, o1 = 4096 + t * 16;
        int r0 = o0 >> 6, s0 = ((o0 >> 4) & 3) ^ ((r0 >> 1) & 3);
        int r1 = o1 >> 6, s1 = ((o1 >> 4) & 3) ^ ((r1 >> 1) & 3);
        int ar0 = m0 + r0; if (ar0 >= M) ar0 = M - 1;
        int ar1 = m0 + r1; if (ar1 >= M) ar1 = M - 1;
        gpa0 = A + (size_t)ar0 * K + s0 * 8;  la0 = o0;
        gpa1 = A + (size_t)ar1 * K + s1 * 8;  la1 = o1;
        gpb0 = Bt + (size_t)(n0 + r0) * K + s0 * 8;  lb0 = 8192 + o0;
        gpb1 = Bt + (size_t)(n0 + r1) * K + s1 * 8;  lb1 = 8192 + o1;
    }

    f32x4 acc[4][4] = {};
    const int nt = K >> 5;      // 24

    // prologue: stage tiles 0 (buf0) and 1 (buf1); 8 loads stay in flight
    gl16(gpa0, &lds[la0]); gl16(gpa1, &lds[la1]);
    gl16(gpb0, &lds[lb0]); gl16(gpb1, &lds[lb1]);
    gpa0 += 32; gpa1 += 32; gpb0 += 32; gpb1 += 32;
    gl16(gpa0, &lds[16384 + la0]); gl16(gpa1, &lds[16384 + la1]);
    gl16(gpb0, &lds[16384 + lb0]); gl16(gpb1, &lds[16384 + lb1]);
    gpa0 += 32; gpa1 += 32; gpb0 += 32; gpb1 += 32;

    int cur = 0;
    for (int tt = 0; tt < nt; ++tt) {
        if (tt + 1 < nt) asm volatile("s_waitcnt vmcnt(4)" ::: "memory");
        else             asm volatile("s_waitcnt vmcnt(0)" ::: "memory");
        __builtin_amdgcn_s_barrier();   // tile tt fully in LDS (all waves)

        // stage tile tt+2 -> buf[(cur+2)%3] (its readers retired at tt-1)
        if (tt + 2 < nt) {
            int nx = cur + 2; if (nx >= 3) nx -= 3;
            char* nb = &lds[nx << 14];
            gl16(gpa0, nb + la0); gl16(gpa1, nb + la1);
            gl16(gpb0, nb + lb0); gl16(gpb1, nb + lb1);
            gpa0 += 32; gpa1 += 32; gpb0 += 32; gpb1 += 32;
        }

        char* base = &lds[cur << 14];
        bf16x8 af[4], bfr[4];
        #pragma unroll
        for (int m = 0; m < 4; ++m) {
            int row = wr * 64 + m * 16 + lm;
            af[m] = *reinterpret_cast<const bf16x8*>(
                base + row * 64 + ((lkg ^ ((row >> 1) & 3)) << 4));
        }
        #pragma unroll
        for (int n = 0; n < 4; ++n) {
            int row = wc * 64 + n * 16 + lm;
            bfr[n] = *reinterpret_cast<const bf16x8*>(
                base + 8192 + row * 64 + ((lkg ^ ((row >> 1) & 3)) << 4));
        }
        __builtin_amdgcn_s_setprio(1);
        #pragma unroll
        for (int m = 0; m < 4; ++m)
            #pragma unroll
            for (int n = 0; n < 4; ++n)
                acc[m][n] = __builtin_amdgcn_mfma_f32_16x16x32_bf16(
                    af[m], bfr[n], acc[m][n], 0, 0, 0);
        __builtin_amdgcn_s_setprio(0);

        cur = (cur == 2) ? 0 : cur + 1;
    }

    // epilogue: row-contiguous store order (n innermost => full 128B lines)
    float bv[4];
    #pragma unroll
    for (int n = 0; n < 4; ++n)
        bv[n] = bias ? bias[n0 + wc * 64 + n * 16 + lm] : 0.f;
    #pragma unroll
    for (int m = 0; m < 4; ++m) {
        #pragma unroll
        for (int r = 0; r < 4; ++r) {
            int row = m0 + wr * 64 + m * 16 + lkg * 4 + r;
            if (row >= M) continue;
            #pragma unroll
            for (int n = 0; n < 4; ++n) {
                int col = n0 + wc * 64 + n * 16 + lm;
                float o = acc[m][n][r] + bv[n];
                if (out_bf16)
                    ((unsigned short*)C)[(size_t)row * N + col] = f2bf(o);
                else
                    ((float*)C)[(size_t)row * N + col] = o;
            }
        }
    }
}

// ---------------------------------------------------------------------------
// Row-tiled depthwise 3x3 pool + LayerNorm (shared body).
// mode 3: q-ext [bh][pos][128] (q*QSCALE, ext zeros, [120]=PADSUP)
// mode 1: k-ext [bh][pos][128] (k, onehot(kh)/onehot(kw))
// mode 2: v^T   [bh][64][NKEYPAD]
// ---------------------------------------------------------------------------
__device__ __forceinline__ void pool_body(
    const unsigned short* src, const float* w, const float* g,
    const float* beta, unsigned short* outp, int bh, int orow,
    int stride, int OW, int mode, unsigned short* ibuf,
    int t, int wave, int lane)
{
    for (int i = t; i < 3 * 56 * 32; i += 256) {
        int pair = i >> 5, off = i & 31;
        int r = pair / 56, iw = pair % 56;
        int ih = orow * stride + r - 1;
        unsigned v = 0;
        if (ih >= 0 && ih < QH)
            v = *reinterpret_cast<const unsigned*>(
                src + (size_t)(1 + ih * QW + iw) * THREE_DIM + off * 2);
        *reinterpret_cast<unsigned*>(&ibuf[pair * 64 + off * 2]) = v;
    }

    float wreg[9];
    #pragma unroll
    for (int k = 0; k < 9; ++k) wreg[k] = w[lane * 9 + k];
    float gl = g[lane], bl = beta[lane];
    __syncthreads();

    int ntask = OW + ((orow == 0) ? 1 : 0);    // extra task: cls (pos 0)
    for (int task = wave; task < ntask; task += 4) {
        float val;
        int pos;
        if (task == OW) {                      // cls token
            val = bf2f(src[lane]);
            pos = 0;
        } else {
            int ow = task;
            float acc = 0.f;
            #pragma unroll
            for (int r = 0; r < 3; ++r) {
                #pragma unroll
                for (int c = 0; c < 3; ++c) {
                    int iwc = ow * stride + c - 1;
                    if (iwc < 0 || iwc >= QW) continue;
                    acc += bf2f(ibuf[(r * 56 + iwc) * 64 + lane]) * wreg[r * 3 + c];
                }
            }
            val = acc;
            pos = 1 + orow * OW + ow;
        }

        float mu = val;
        #pragma unroll
        for (int off = 32; off > 0; off >>= 1) mu += __shfl_xor(mu, off, 64);
        mu *= (1.f / 64.f);
        float dv = val - mu;
        float var = dv * dv;
        #pragma unroll
        for (int off = 32; off > 0; off >>= 1) var += __shfl_xor(var, off, 64);
        var *= (1.f / 64.f);
        float o = dv * rsqrtf(var + 1e-5f) * gl + bl;

        if (mode == 3) {
            unsigned short* row = outp + ((size_t)bh * NTOK + pos) * XD;
            row[lane] = f2bf(o * QSCALE);
            row[64 + lane] = (lane == 56) ? f2bf(PADSUP) : 0;
        } else if (mode == 1) {
            unsigned short* row = outp + ((size_t)bh * NKEYPAD + pos) * XD;
            row[lane] = f2bf(o);
            unsigned short ext = 0;
            if (pos > 0) {
                int kh = (pos - 1) / 28, kw = (pos - 1) % 28;
                if ((lane < 28 && lane == kh) ||
                    (lane >= 28 && lane < 56 && lane - 28 == kw))
                    ext = 0x3F80;   // 1.0 bf16
            }
            row[64 + lane] = ext;
        } else {
            outp[((size_t)bh * HD + lane) * NKEYPAD + pos] = f2bf(o);
        }
    }
}

__global__ __launch_bounds__(256) void pool_ln_q(
    const unsigned short* __restrict__ qkvb, const float* __restrict__ w,
    const float* __restrict__ g, const float* __restrict__ beta,
    unsigned short* __restrict__ outp)
{
    __shared__ unsigned short ibuf[3 * 56 * 64];
    int bid = blockIdx.x;
    int orow = bid % QH;
    int bh = bid / QH;
    int head = bh % NHEAD, b = bh / NHEAD;
    const unsigned short* src =
        qkvb + (size_t)b * NTOK * THREE_DIM + (size_t)head * HD;
    pool_body(src, w, g, beta, outp, bh, orow, 1, QW, 3, ibuf,
              threadIdx.x, threadIdx.x >> 6, threadIdx.x & 63);
}

// k (y=0) and v (y=1) pools in one launch
__global__ __launch_bounds__(256) void pool_ln_kv(
    const unsigned short* __restrict__ qkvb,
    const float* __restrict__ wk, const float* __restrict__ gk,
    const float* __restrict__ bk, unsigned short* __restrict__ kpx,
    const float* __restrict__ wv, const float* __restrict__ gv,
    const float* __restrict__ bv, unsigned short* __restrict__ vt16)
{
    __shared__ unsigned short ibuf[3 * 56 * 64];
    int bid = blockIdx.x;
    int orow = bid % 28;
    int bh = bid / 28;
    int head = bh % NHEAD, b = bh / NHEAD;
    int isv = blockIdx.y;
    const unsigned short* src = qkvb + (size_t)b * NTOK * THREE_DIM
        + (size_t)(isv ? 2 : 1) * DIM + (size_t)head * HD;
    if (isv)
        pool_body(src, wv, gv, bv, vt16, bh, orow, 2, 28, 2, ibuf,
                  threadIdx.x, threadIdx.x >> 6, threadIdx.x & 63);
    else
        pool_body(src, wk, gk, bk, kpx, bh, orow, 2, 28, 1, ibuf,
                  threadIdx.x, threadIdx.x >> 6, threadIdx.x & 63);
}

// ---------------------------------------------------------------------------
// Pad rows (785..799): k-ext rows = pad-flag onehot; v^T pad cols = 0.
// ---------------------------------------------------------------------------
__global__ __launch_bounds__(64) void pad_kv(
    unsigned short* __restrict__ kpx, unsigned short* __restrict__ vt16)
{
    int bh = blockIdx.x;
    int t = threadIdx.x;
    for (int pos = NKEY; pos < NKEYPAD; ++pos) {
        unsigned short* row = kpx + ((size_t)bh * NKEYPAD + pos) * XD;
        row[t] = 0;
        row[64 + t] = (t == 56) ? 0x3F80 : 0;
        vt16[((size_t)bh * HD + t) * NKEYPAD + pos] = 0;
    }
}

// ---------------------------------------------------------------------------
// MFMA rel-pos dots -> bf16 Q-ext columns of qpx. blockIdx.z = mode.
// ---------------------------------------------------------------------------
__global__ __launch_bounds__(256) void rel_mfma(
    const unsigned short* __restrict__ qpx, const unsigned short* __restrict__ rh,
    const unsigned short* __restrict__ rw, unsigned short* __restrict__ qpx_out)
{
    __shared__ char bbuf[4096];     // [32 rows][64 bf16], XOR-swizzled
    int X = blockIdx.x;
    int m0 = blockIdx.y * 256;
    int mode = blockIdx.z;
    const unsigned short* rtab = mode ? rw : rh;
    int t = threadIdx.x;
    int wave = t >> 6, lane = t & 63;
    int lm = lane & 15, lkg = lane >> 4;

    {
        int row = t >> 3, c8 = t & 7;
        int4 val = {0, 0, 0, 0};
        if (row < 28) {
            int dh = X - 2 * row + 54;              // in [0, 110)
            val = *reinterpret_cast<const int4*>(rtab + (size_t)dh * HD + c8 * 8);
        }
        *reinterpret_cast<int4*>(&bbuf[row * 128 + ((c8 * 16) ^ ((row & 7) << 4))]) = val;
    }
    __syncthreads();

    int rbase = m0 + wave * 64 + lm;
    f32x4 acc[4][2] = {};
    #pragma unroll
    for (int kc = 0; kc < 2; ++kc) {
        bf16x8 bfrag[2];
        #pragma unroll
        for (int nb = 0; nb < 2; ++nb) {
            int row = nb * 16 + lm;
            bfrag[nb] = *reinterpret_cast<const bf16x8*>(
                &bbuf[row * 128 + (((kc * 4 + lkg) * 16) ^ ((row & 7) << 4))]);
        }
        #pragma unroll
        for (int m = 0; m < 4; ++m) {
            int rho = rbase + m * 16; if (rho > RELROWS - 1) rho = RELROWS - 1;
            int bh = rho / 56, rem = rho % 56;
            int pos1 = (mode == 0) ? X * 56 + rem : rem * 56 + X;
            const unsigned short* qsrc =
                qpx + ((size_t)bh * NTOK + 1 + pos1) * XD + kc * 32 + lkg * 8;
            bf16x8 af = *reinterpret_cast<const bf16x8*>(qsrc);
            acc[m][0] = __builtin_amdgcn_mfma_f32_16x16x32_bf16(af, bfrag[0], acc[m][0], 0, 0, 0);
            acc[m][1] = __builtin_amdgcn_mfma_f32_16x16x32_bf16(af, bfrag[1], acc[m][1], 0, 0, 0);
        }
    }

    #pragma unroll
    for (int m = 0; m < 4; ++m) {
        #pragma unroll
        for (int r = 0; r < 4; ++r) {
            int rho = m0 + wave * 64 + m * 16 + lkg * 4 + r;
            if (rho >= RELROWS) continue;
            int bh = rho / 56, rem = rho % 56;
            int pos1 = (mode == 0) ? X * 56 + rem : rem * 56 + X;
            unsigned short* dst =
                qpx_out + ((size_t)bh * NTOK + 1 + pos1) * XD + 64 + mode * 28;
            dst[lm] = f2bf(acc[m][0][r] * 8.f);             // -> log2e * (q.r)
            if (lm < 12) dst[16 + lm] = f2bf(acc[m][1][r] * 8.f);
        }
    }
}

// ---------------------------------------------------------------------------
// MFMA flash attention, 8 waves x 32 q-rows (QT=256, 512 thr), swapped QK
// (mfma(K,Q): lane holds q=lm, keys lkg*4+r), bias in ext-128 K-dim, 3-stage
// pipeline (counted vmcnt(2), ONE barrier/iter), XCD swizzle, exp2 scores.
// launch_bounds(512,4): VGPR cap 128 -- fits ~100 live regs, NO SPILL
// (r15's (512,6) capped at 85 and spilled accumulators -> 1.1GB scratch).
// K staging: 1 chunk/thread (512x16B = 8KB exact). V staging: duplicate-
// write trick (vidx = t&255) preserving wave-uniform-base semantics and a
// uniform 2 loads/thread per tile (counted-vmcnt correctness).
// osum partials reduced over lkg groups (shfl_xor 16/32) before reciprocal.
// ---------------------------------------------------------------------------
__global__ __launch_bounds__(512, 4) void attn_mfma(
    const unsigned short* __restrict__ qpx, const unsigned short* __restrict__ kpx,
    const unsigned short* __restrict__ vt, unsigned short* __restrict__ outp)
{
    __shared__ __align__(16) char kbuf[3][8192];   // Kext tile [32][128] bf16
    __shared__ __align__(16) char vbuf[3][4096];   // Vt tile  [64][32]  bf16
    __shared__ __align__(16) char pbuf[8][2048];   // per-wave P [32 q][32 k]

    int bid0 = blockIdx.x;
    int bid = (bid0 & 7) * ((NBH * NQB) / 8) + (bid0 >> 3);   // 624 % 8 == 0
    int tile = bid % NQB;
    int bh = bid / NQB;
    int head = bh % NHEAD, b = bh / NHEAD;
    int q0 = tile * QTB;
    int t = threadIdx.x;
    int wave = t >> 6, lane = t & 63;
    int lm = lane & 15, lkg = lane >> 4;

    const unsigned short* kb  = kpx + (size_t)bh * NKEYPAD * XD;
    const unsigned short* vtb = vt + (size_t)bh * HD * NKEYPAD;

    // Q fragments: 2 row-blocks x 4 chunks of 32 ext-dims (wave owns 32 rows)
    bf16x8 qf[2][4] = {};
    #pragma unroll
    for (int rb = 0; rb < 2; ++rb) {
        int qrow = q0 + wave * 32 + rb * 16 + lm;
        if (qrow < NTOK) {
            const unsigned short* qs = qpx + ((size_t)bh * NTOK + qrow) * XD + lkg * 8;
            qf[rb][0] = *reinterpret_cast<const bf16x8*>(qs);
            qf[rb][1] = *reinterpret_cast<const bf16x8*>(qs + 32);
            qf[rb][2] = *reinterpret_cast<const bf16x8*>(qs + 64);
            qf[rb][3] = *reinterpret_cast<const bf16x8*>(qs + 96);
        }
    }

    f32x4 oacc[2][4] = {};
    float osum[2] = {0.f, 0.f};    // partial per lane: q = lm, keys of lkg grp

    // K staging: 1 chunk/thread, 512 x 16B = 8KB tile exactly.
    int kr = t >> 4;                 // rows 0..31
    int ks = (t & 15) ^ (kr & 7);    // pre-swizzled source slot
    const unsigned short* kp0 = kb + (size_t)kr * XD + ks * 8;
    int kd = t * 16;
    // V staging: duplicate across wave-halves (vidx = t & 255).
    int vidx = t & 255;
    int vr = vidx >> 2;
    int vs = (vidx & 3) ^ ((vr >> 1) & 3);
    const unsigned short* vp0 = vtb + (size_t)vr * NKEYPAD + vs * 8;
    int vd = vidx * 16;              // = (wave&3)*1024 + lane*16 (uniform base)

    const int NT = NKEYPAD / 32;   // 25

    // prologue: stage tiles 0,1 (2 loads per thread per tile)
    gl16(kp0, &kbuf[0][kd]); gl16(vp0, &vbuf[0][vd]);
    kp0 += 32 * XD; vp0 += 32;
    gl16(kp0, &kbuf[1][kd]); gl16(vp0, &vbuf[1][vd]);
    kp0 += 32 * XD; vp0 += 32;

    // P write address base: byte(P[q][k]) = (k>>3)*256 + q*16 + (k&7)*2
    int pwbase = lm * 16 + ((lkg & 1) << 3);   // + (nb*2 + (lkg>>1))*256 + rb*1024

    int cur = 0;
    for (int jt = 0; jt < NT; ++jt) {
        if (jt + 1 < NT) asm volatile("s_waitcnt vmcnt(2)" ::: "memory");
        else             asm volatile("s_waitcnt vmcnt(0)" ::: "memory");
        __builtin_amdgcn_s_barrier();   // tile jt fully in LDS

        // stage tile jt+2 into buf[(jt+2)%3] (last read at jt-1, retired)
        if (jt + 2 < NT) {
            int nx = cur + 2; if (nx >= 3) nx -= 3;
            gl16(kp0, &kbuf[nx][kd]);
            gl16(vp0, &vbuf[nx][vd]);
            kp0 += 32 * XD; vp0 += 32;
        }

        // Swapped QK^T: S[k][q] = mfma(Kext, Qext); kf shared across both rb
        f32x4 a00 = {0.f,0.f,0.f,0.f}, a01 = {0.f,0.f,0.f,0.f};
        f32x4 a10 = {0.f,0.f,0.f,0.f}, a11 = {0.f,0.f,0.f,0.f};
        __builtin_amdgcn_s_setprio(1);
        #pragma unroll
        for (int kc = 0; kc < 4; ++kc) {
            int sl = (kc * 4 + lkg) ^ (lm & 7);
            bf16x8 kf0 = *reinterpret_cast<const bf16x8*>(&kbuf[cur][lm * 256 + sl * 16]);
            bf16x8 kf1 = *reinterpret_cast<const bf16x8*>(&kbuf[cur][(16 + lm) * 256 + sl * 16]);
            a00 = __builtin_amdgcn_mfma_f32_16x16x32_bf16(kf0, qf[0][kc], a00, 0, 0, 0);
            a01 = __builtin_amdgcn_mfma_f32_16x16x32_bf16(kf1, qf[0][kc], a01, 0, 0, 0);
            a10 = __builtin_amdgcn_mfma_f32_16x16x32_bf16(kf0, qf[1][kc], a10, 0, 0, 0);
            a11 = __builtin_amdgcn_mfma_f32_16x16x32_bf16(kf1, qf[1][kc], a11, 0, 0, 0);
        }
        __builtin_amdgcn_s_setprio(0);

        // exp2 + pack pairs + b64 write (4 consecutive k per write)
        #pragma unroll
        for (int rb = 0; rb < 2; ++rb) {
            #pragma unroll
            for (int nb = 0; nb < 2; ++nb) {
                f32x4 a = rb ? (nb ? a11 : a10) : (nb ? a01 : a00);
                float e0, e1, e2, e3;
                asm("v_exp_f32 %0, %1" : "=v"(e0) : "v"(a[0]));
                asm("v_exp_f32 %0, %1" : "=v"(e1) : "v"(a[1]));
                asm("v_exp_f32 %0, %1" : "=v"(e2) : "v"(a[2]));
                asm("v_exp_f32 %0, %1" : "=v"(e3) : "v"(a[3]));
                osum[rb] += (e0 + e1) + (e2 + e3);
                union { float f; unsigned u; } u0, u1, u2, u3;
                u0.f = e0; u1.f = e1; u2.f = e2; u3.f = e3;
                uint2 pk;
                pk.x = (u0.u >> 16) | (u1.u & 0xFFFF0000u);   // k+0, k+1
                pk.y = (u2.u >> 16) | (u3.u & 0xFFFF0000u);   // k+2, k+3
                int addr = (rb << 10) + ((nb * 2 + (lkg >> 1)) << 8) + pwbase;
                *reinterpret_cast<uint2*>(&pbuf[wave][addr]) = pk;
            }
        }

        // PV: O[rb] += P[rb][16x32] * Vt ; pf read is lane-linear (no conflict)
        bf16x8 pf0 = *reinterpret_cast<const bf16x8*>(&pbuf[wave][lane * 16]);
        bf16x8 pf1 = *reinterpret_cast<const bf16x8*>(&pbuf[wave][1024 + lane * 16]);
        __builtin_amdgcn_s_setprio(1);
        #pragma unroll
        for (int db = 0; db < 4; ++db) {
            int row = db * 16 + lm;
            bf16x8 vf = *reinterpret_cast<const bf16x8*>(
                &vbuf[cur][row * 64 + ((lkg ^ ((row >> 1) & 3)) << 4)]);
            oacc[0][db] = __builtin_amdgcn_mfma_f32_16x16x32_bf16(pf0, vf, oacc[0][db], 0, 0, 0);
            oacc[1][db] = __builtin_amdgcn_mfma_f32_16x16x32_bf16(pf1, vf, oacc[1][db], 0, 0, 0);
        }
        __builtin_amdgcn_s_setprio(0);

        cur = (cur == 2) ? 0 : cur + 1;
    }

    // FULL denominator: reduce partials across the 4 lkg groups (bits 4,5),
    // then lane-local reciprocal; broadcast to output layout via shfl.
    #pragma unroll
    for (int rb = 0; rb < 2; ++rb) {
        osum[rb] += __shfl_xor(osum[rb], 16, 64);
        osum[rb] += __shfl_xor(osum[rb], 32, 64);
    }
    float inv[2] = { 1.f / osum[0], 1.f / osum[1] };
    #pragma unroll
    for (int rb = 0; rb < 2; ++rb) {
        #pragma unroll
        for (int r = 0; r < 4; ++r) {
            float invq = __shfl(inv[rb], lkg * 4 + r, 64);   // lane with lm = q
            int qpos = q0 + wave * 32 + rb * 16 + lkg * 4 + r;
            if (qpos >= NTOK) continue;
            unsigned short* orow = outp + ((size_t)b * NTOK + qpos) * DIM + (size_t)head * HD;
            const unsigned short* qres = qpx + ((size_t)bh * NTOK + qpos) * XD;
            #pragma unroll
            for (int db = 0; db < 4; ++db) {
                int d = db * 16 + lm;
                float o = oacc[rb][db][r] * invq;
                if (qpos > 0) o += bf2f(qres[d]) * QUNSCALE;   // residual
                orow[d] = f2bf(o);
            }
        }
    }
}

// ---------------------------------------------------------------------------
extern "C" void kernel_launch(void* const* d_in, const int* in_sizes, int n_in,
                              void* d_out, int out_size, void* d_ws, size_t ws_size,
                              hipStream_t stream) {
    const float* x     = (const float*)d_in[0];
    const float* Wqkv  = (const float*)d_in[1];
    const float* pqw   = (const float*)d_in[2];
    const float* pkw   = (const float*)d_in[3];
    const float* pvw   = (const float*)d_in[4];
    const float* gq    = (const float*)d_in[5];
    const float* bq    = (const float*)d_in[6];
    const float* gk    = (const float*)d_in[7];
    const float* bk    = (const float*)d_in[8];
    const float* gv    = (const float*)d_in[9];
    const float* bv    = (const float*)d_in[10];
    const float* rph   = (const float*)d_in[11];
    const float* rpw   = (const float*)d_in[12];
    const float* Wproj = (const float*)d_in[13];
    const float* bproj = (const float*)d_in[14];

    unsigned short* qkvb  = (unsigned short*)d_ws;                 // [M][2304] bf16
    unsigned short* qpx   = qkvb + (size_t)MROWS * THREE_DIM;      // [48][3137][128]
    unsigned short* kpx   = qpx + (size_t)NBH * NTOK * XD;         // [48][800][128]
    unsigned short* vt16  = kpx + (size_t)NBH * NKEYPAD * XD;      // [48][64][800]
    unsigned short* xbf   = vt16 + (size_t)NBH * HD * NKEYPAD;     // [M][768]
    unsigned short* wqkvt = xbf + (size_t)MROWS * DIM;             // [2304][768]
    unsigned short* wprojt= wqkvt + (size_t)DIM * THREE_DIM;       // [768][768]
    unsigned short* rphb  = wprojt + (size_t)DIM * DIM;            // [111][64]
    unsigned short* rpwb  = rphb + 7104;
    unsigned short* attn_bf = qkvb;            // alias (qkvb dead after pools)

    dim3 blk(256);

    // 0) bf16 conversions (consolidated)
    cvt_bf16<<<2048, blk, 0, stream>>>(x, xbf, (int)((size_t)MROWS * DIM / 4));
    {
        dim3 g(THREE_DIM / 32, DIM / 32, 2);
        transpose_bf16_2<<<g, blk, 0, stream>>>(Wqkv, wqkvt, Wproj, wprojt);
    }
    cvt_rel<<<14, blk, 0, stream>>>(rph, rpw, rphb, rpwb);

    // 1) qkv = x @ Wqkv   (bf16 MFMA 128^2 pipelined, bf16 out)
    {
        dim3 grid(THREE_DIM / 128, (MROWS + 127) / 128);
        gemm_mfma<<<grid, blk, 0, stream>>>(xbf, wqkvt, nullptr, qkvb,
                                            MROWS, THREE_DIM, DIM, 1);
    }

    // 2) pool + LN: q-ext; k-ext + v^T merged; then pad rows
    pool_ln_q<<<NBH * QH, blk, 0, stream>>>(qkvb, pqw, gq, bq, qpx);
    {
        dim3 g(NBH * 28, 2);
        pool_ln_kv<<<g, blk, 0, stream>>>(qkvb, pkw, gk, bk, kpx,
                                          pvw, gv, bv, vt16);
    }
    pad_kv<<<NBH, 64, 0, stream>>>(kpx, vt16);

    // 3) rel-pos dots -> Q-ext columns (bf16, in-place into qpx), both modes
    {
        dim3 g(56, (RELROWS + 255) / 256, 2);
        rel_mfma<<<g, blk, 0, stream>>>(qpx, rphb, rpwb, qpx);
    }

    // 4) MFMA flash attention (bias folded, exp2 scores, 8 waves/block)
    attn_mfma<<<NBH * NQB, 512, 0, stream>>>(qpx, kpx, vt16, attn_bf);

    // 5) out = attn_out @ Wproj + bproj   (bf16 MFMA, fp32 out)
    {
        dim3 grid(DIM / 128, (MROWS + 127) / 128);
        gemm_mfma<<<grid, blk, 0, stream>>>(attn_bf, wprojt, bproj, d_out,
                                            MROWS, DIM, DIM, 0);
    }
}

// Round 17
// 276.868 us; speedup vs baseline: 1.7553x; 1.0147x over previous
//
#include <hip/hip_runtime.h>
#include <hip/hip_bf16.h>

// Problem constants (fixed by setup_inputs)
#define BATCH 4
#define NTOK 3137        // 1 + 56*56
#define DIM 768
#define NHEAD 12
#define HD 64
#define QH 56
#define QW 56
#define NKEY 785         // 1 + 28*28
#define NKEYPAD 800      // padded key count (25 x 32)
#define THREE_DIM 2304
#define MROWS (BATCH*NTOK)   // 12548
#define QT2 128              // attn q-tile (4 waves x 32 rows)
#define NQT2 25              // ceil(3137/128)
#define NBH 48               // BATCH*NHEAD
#define RELROWS (NBH*56)     // 2688
#define XD 128               // extended head dim (64 q + 28 relh + 28 relw + pad flag)

// exp2 folding: q pre-scale = 0.125 * log2(e); scores come out in log2 units
#define QSCALE 0.1803368801111204f
#define QUNSCALE 5.5451774444795625f   // 1/QSCALE (residual recovery)
#define PADSUP  -43.3f                 // -30 * log2(e)

typedef __attribute__((ext_vector_type(8))) short bf16x8;
typedef __attribute__((ext_vector_type(4))) float f32x4;

__device__ __forceinline__ unsigned short f2bf(float f) {
    union { float f; unsigned u; } v; v.f = f;
    unsigned r = v.u + 0x7FFFu + ((v.u >> 16) & 1u);   // RNE
    return (unsigned short)(r >> 16);
}
__device__ __forceinline__ float bf2f(unsigned short s) {
    union { unsigned u; float f; } v; v.u = (unsigned)s << 16; return v.f;
}

__device__ __forceinline__ void gl16(const void* g, void* l) {
    __builtin_amdgcn_global_load_lds(
        (const __attribute__((address_space(1))) unsigned int*)g,
        (__attribute__((address_space(3))) unsigned int*)l, 16, 0, 0);
}

// ---------------------------------------------------------------------------
// fp32 -> bf16 elementwise (vectorized x4)
// ---------------------------------------------------------------------------
__global__ __launch_bounds__(256) void cvt_bf16(
    const float* __restrict__ in, unsigned short* __restrict__ outp, int n4)
{
    for (int i = blockIdx.x * 256 + threadIdx.x; i < n4; i += gridDim.x * 256) {
        float4 v = reinterpret_cast<const float4*>(in)[i];
        union { unsigned short s[4]; uint2 u; } o;
        o.s[0] = f2bf(v.x); o.s[1] = f2bf(v.y);
        o.s[2] = f2bf(v.z); o.s[3] = f2bf(v.w);
        reinterpret_cast<uint2*>(outp)[i] = o.u;
    }
}

// Both rel tables in one launch (n4 = 1776 each)
__global__ __launch_bounds__(256) void cvt_rel(
    const float* __restrict__ h, const float* __restrict__ w,
    unsigned short* __restrict__ hb, unsigned short* __restrict__ wb)
{
    int i = blockIdx.x * 256 + threadIdx.x;
    const float* src; unsigned short* dst; int j;
    if (i < 1776)      { src = h; dst = hb; j = i; }
    else if (i < 3552) { src = w; dst = wb; j = i - 1776; }
    else return;
    float4 v = reinterpret_cast<const float4*>(src)[j];
    union { unsigned short s[4]; uint2 u; } o;
    o.s[0] = f2bf(v.x); o.s[1] = f2bf(v.y);
    o.s[2] = f2bf(v.z); o.s[3] = f2bf(v.w);
    reinterpret_cast<uint2*>(dst)[j] = o.u;
}

// ---------------------------------------------------------------------------
// W[K][N] fp32 -> Wt[N][K] bf16; z=0: Wqkv(768x2304), z=1: Wproj(768x768)
// ---------------------------------------------------------------------------
__global__ __launch_bounds__(256) void transpose_bf16_2(
    const float* __restrict__ W0, unsigned short* __restrict__ Wt0,
    const float* __restrict__ W1, unsigned short* __restrict__ Wt1)
{
    const float* W; unsigned short* Wt; int N;
    if (blockIdx.z == 0) { W = W0; Wt = Wt0; N = THREE_DIM; }
    else {
        if (blockIdx.x >= DIM / 32) return;
        W = W1; Wt = Wt1; N = DIM;
    }
    const int K = DIM;
    __shared__ float tile[32][33];
    int k0 = blockIdx.y * 32, n0 = blockIdx.x * 32;
    int t = threadIdx.x;
    int r = t >> 5, c = t & 31;
    #pragma unroll
    for (int p = 0; p < 4; ++p)
        tile[r + p * 8][c] = W[(size_t)(k0 + r + p * 8) * N + n0 + c];
    __syncthreads();
    #pragma unroll
    for (int p = 0; p < 4; ++p)
        Wt[(size_t)(n0 + r + p * 8) * K + k0 + c] = f2bf(tile[c][r + p * 8]);
}

// ---------------------------------------------------------------------------
// bf16 MFMA GEMM, 128x128 tile, 4 waves (2x2), BK=32, 3-stage LDS pipeline
// (48 KB), counted vmcnt(4), ONE top barrier per iter. setprio around MFMA.
// ---------------------------------------------------------------------------
__global__ __launch_bounds__(256, 3) void gemm_mfma(
    const unsigned short* __restrict__ A, const unsigned short* __restrict__ Bt,
    const float* __restrict__ bias, void* __restrict__ C,
    int M, int N, int K, int out_bf16)
{
    __shared__ __align__(16) char lds[49152];   // 3 stages x (A 8K | B 8K)
    int t = threadIdx.x;
    int wave = t >> 6, lane = t & 63;
    int lm = lane & 15, lkg = lane >> 4;
    int wr = wave >> 1, wc = wave & 1;

    // bijective XCD remap (m204)
    int gx = gridDim.x;
    int nwg = gx * gridDim.y;
    int lin = blockIdx.y * gx + blockIdx.x;
    int qq = nwg >> 3, rr = nwg & 7;
    int xcd = lin & 7, idx = lin >> 3;
    int newlin = (xcd < rr ? xcd * (qq + 1) : rr * (qq + 1) + (xcd - rr) * qq) + idx;
    int m0 = (newlin / gx) * 128, n0 = (newlin % gx) * 128;

    // staging roles: 2 chunks per matrix per thread, pre-swizzled source
    const unsigned short *gpa0, *gpa1, *gpb0, *gpb1;
    int la0, la1, lb0, lb1;
    {
        int o0 = t * 16, o1 = 4096 + t * 16;
        int r0 = o0 >> 6, s0 = ((o0 >> 4) & 3) ^ ((r0 >> 1) & 3);
        int r1 = o1 >> 6, s1 = ((o1 >> 4) & 3) ^ ((r1 >> 1) & 3);
        int ar0 = m0 + r0; if (ar0 >= M) ar0 = M - 1;
        int ar1 = m0 + r1; if (ar1 >= M) ar1 = M - 1;
        gpa0 = A + (size_t)ar0 * K + s0 * 8;  la0 = o0;
        gpa1 = A + (size_t)ar1 * K + s1 * 8;  la1 = o1;
        gpb0 = Bt + (size_t)(n0 + r0) * K + s0 * 8;  lb0 = 8192 + o0;
        gpb1 = Bt + (size_t)(n0 + r1) * K + s1 * 8;  lb1 = 8192 + o1;
    }

    f32x4 acc[4][4] = {};
    const int nt = K >> 5;      // 24

    // prologue: stage tiles 0 (buf0) and 1 (buf1); 8 loads stay in flight
    gl16(gpa0, &lds[la0]); gl16(gpa1, &lds[la1]);
    gl16(gpb0, &lds[lb0]); gl16(gpb1, &lds[lb1]);
    gpa0 += 32; gpa1 += 32; gpb0 += 32; gpb1 += 32;
    gl16(gpa0, &lds[16384 + la0]); gl16(gpa1, &lds[16384 + la1]);
    gl16(gpb0, &lds[16384 + lb0]); gl16(gpb1, &lds[16384 + lb1]);
    gpa0 += 32; gpa1 += 32; gpb0 += 32; gpb1 += 32;

    int cur = 0;
    for (int tt = 0; tt < nt; ++tt) {
        if (tt + 1 < nt) asm volatile("s_waitcnt vmcnt(4)" ::: "memory");
        else             asm volatile("s_waitcnt vmcnt(0)" ::: "memory");
        __builtin_amdgcn_s_barrier();   // tile tt fully in LDS (all waves)

        // stage tile tt+2 -> buf[(cur+2)%3] (its readers retired at tt-1)
        if (tt + 2 < nt) {
            int nx = cur + 2; if (nx >= 3) nx -= 3;
            char* nb = &lds[nx << 14];
            gl16(gpa0, nb + la0); gl16(gpa1, nb + la1);
            gl16(gpb0, nb + lb0); gl16(gpb1, nb + lb1);
            gpa0 += 32; gpa1 += 32; gpb0 += 32; gpb1 += 32;
        }

        char* base = &lds[cur << 14];
        bf16x8 af[4], bfr[4];
        #pragma unroll
        for (int m = 0; m < 4; ++m) {
            int row = wr * 64 + m * 16 + lm;
            af[m] = *reinterpret_cast<const bf16x8*>(
                base + row * 64 + ((lkg ^ ((row >> 1) & 3)) << 4));
        }
        #pragma unroll
        for (int n = 0; n < 4; ++n) {
            int row = wc * 64 + n * 16 + lm;
            bfr[n] = *reinterpret_cast<const bf16x8*>(
                base + 8192 + row * 64 + ((lkg ^ ((row >> 1) & 3)) << 4));
        }
        __builtin_amdgcn_s_setprio(1);
        #pragma unroll
        for (int m = 0; m < 4; ++m)
            #pragma unroll
            for (int n = 0; n < 4; ++n)
                acc[m][n] = __builtin_amdgcn_mfma_f32_16x16x32_bf16(
                    af[m], bfr[n], acc[m][n], 0, 0, 0);
        __builtin_amdgcn_s_setprio(0);

        cur = (cur == 2) ? 0 : cur + 1;
    }

    // epilogue: row-contiguous store order (n innermost => full 128B lines)
    float bv[4];
    #pragma unroll
    for (int n = 0; n < 4; ++n)
        bv[n] = bias ? bias[n0 + wc * 64 + n * 16 + lm] : 0.f;
    #pragma unroll
    for (int m = 0; m < 4; ++m) {
        #pragma unroll
        for (int r = 0; r < 4; ++r) {
            int row = m0 + wr * 64 + m * 16 + lkg * 4 + r;
            if (row >= M) continue;
            #pragma unroll
            for (int n = 0; n < 4; ++n) {
                int col = n0 + wc * 64 + n * 16 + lm;
                float o = acc[m][n][r] + bv[n];
                if (out_bf16)
                    ((unsigned short*)C)[(size_t)row * N + col] = f2bf(o);
                else
                    ((float*)C)[(size_t)row * N + col] = o;
            }
        }
    }
}

// ---------------------------------------------------------------------------
// Row-tiled depthwise 3x3 pool + LayerNorm (shared body).
// mode 3: q-ext [bh][pos][128] (q*QSCALE, ext zeros, [120]=PADSUP)
// mode 1: k-ext [bh][pos][128] (k, onehot(kh)/onehot(kw))
// mode 2: v^T   [bh][64][NKEYPAD]
// ---------------------------------------------------------------------------
__device__ __forceinline__ void pool_body(
    const unsigned short* src, const float* w, const float* g,
    const float* beta, unsigned short* outp, int bh, int orow,
    int stride, int OW, int mode, unsigned short* ibuf,
    int t, int wave, int lane)
{
    for (int i = t; i < 3 * 56 * 32; i += 256) {
        int pair = i >> 5, off = i & 31;
        int r = pair / 56, iw = pair % 56;
        int ih = orow * stride + r - 1;
        unsigned v = 0;
        if (ih >= 0 && ih < QH)
            v = *reinterpret_cast<const unsigned*>(
                src + (size_t)(1 + ih * QW + iw) * THREE_DIM + off * 2);
        *reinterpret_cast<unsigned*>(&ibuf[pair * 64 + off * 2]) = v;
    }

    float wreg[9];
    #pragma unroll
    for (int k = 0; k < 9; ++k) wreg[k] = w[lane * 9 + k];
    float gl = g[lane], bl = beta[lane];
    __syncthreads();

    int ntask = OW + ((orow == 0) ? 1 : 0);    // extra task: cls (pos 0)
    for (int task = wave; task < ntask; task += 4) {
        float val;
        int pos;
        if (task == OW) {                      // cls token
            val = bf2f(src[lane]);
            pos = 0;
        } else {
            int ow = task;
            float acc = 0.f;
            #pragma unroll
            for (int r = 0; r < 3; ++r) {
                #pragma unroll
                for (int c = 0; c < 3; ++c) {
                    int iwc = ow * stride + c - 1;
                    if (iwc < 0 || iwc >= QW) continue;
                    acc += bf2f(ibuf[(r * 56 + iwc) * 64 + lane]) * wreg[r * 3 + c];
                }
            }
            val = acc;
            pos = 1 + orow * OW + ow;
        }

        float mu = val;
        #pragma unroll
        for (int off = 32; off > 0; off >>= 1) mu += __shfl_xor(mu, off, 64);
        mu *= (1.f / 64.f);
        float dv = val - mu;
        float var = dv * dv;
        #pragma unroll
        for (int off = 32; off > 0; off >>= 1) var += __shfl_xor(var, off, 64);
        var *= (1.f / 64.f);
        float o = dv * rsqrtf(var + 1e-5f) * gl + bl;

        if (mode == 3) {
            unsigned short* row = outp + ((size_t)bh * NTOK + pos) * XD;
            row[lane] = f2bf(o * QSCALE);
            row[64 + lane] = (lane == 56) ? f2bf(PADSUP) : 0;
        } else if (mode == 1) {
            unsigned short* row = outp + ((size_t)bh * NKEYPAD + pos) * XD;
            row[lane] = f2bf(o);
            unsigned short ext = 0;
            if (pos > 0) {
                int kh = (pos - 1) / 28, kw = (pos - 1) % 28;
                if ((lane < 28 && lane == kh) ||
                    (lane >= 28 && lane < 56 && lane - 28 == kw))
                    ext = 0x3F80;   // 1.0 bf16
            }
            row[64 + lane] = ext;
        } else {
            outp[((size_t)bh * HD + lane) * NKEYPAD + pos] = f2bf(o);
        }
    }
}

__global__ __launch_bounds__(256) void pool_ln_q(
    const unsigned short* __restrict__ qkvb, const float* __restrict__ w,
    const float* __restrict__ g, const float* __restrict__ beta,
    unsigned short* __restrict__ outp)
{
    __shared__ unsigned short ibuf[3 * 56 * 64];
    int bid = blockIdx.x;
    int orow = bid % QH;
    int bh = bid / QH;
    int head = bh % NHEAD, b = bh / NHEAD;
    const unsigned short* src =
        qkvb + (size_t)b * NTOK * THREE_DIM + (size_t)head * HD;
    pool_body(src, w, g, beta, outp, bh, orow, 1, QW, 3, ibuf,
              threadIdx.x, threadIdx.x >> 6, threadIdx.x & 63);
}

// k (y=0) and v (y=1) pools in one launch
__global__ __launch_bounds__(256) void pool_ln_kv(
    const unsigned short* __restrict__ qkvb,
    const float* __restrict__ wk, const float* __restrict__ gk,
    const float* __restrict__ bk, unsigned short* __restrict__ kpx,
    const float* __restrict__ wv, const float* __restrict__ gv,
    const float* __restrict__ bv, unsigned short* __restrict__ vt16)
{
    __shared__ unsigned short ibuf[3 * 56 * 64];
    int bid = blockIdx.x;
    int orow = bid % 28;
    int bh = bid / 28;
    int head = bh % NHEAD, b = bh / NHEAD;
    int isv = blockIdx.y;
    const unsigned short* src = qkvb + (size_t)b * NTOK * THREE_DIM
        + (size_t)(isv ? 2 : 1) * DIM + (size_t)head * HD;
    if (isv)
        pool_body(src, wv, gv, bv, vt16, bh, orow, 2, 28, 2, ibuf,
                  threadIdx.x, threadIdx.x >> 6, threadIdx.x & 63);
    else
        pool_body(src, wk, gk, bk, kpx, bh, orow, 2, 28, 1, ibuf,
                  threadIdx.x, threadIdx.x >> 6, threadIdx.x & 63);
}

// ---------------------------------------------------------------------------
// Pad rows (785..799): k-ext rows = pad-flag onehot; v^T pad cols = 0.
// ---------------------------------------------------------------------------
__global__ __launch_bounds__(64) void pad_kv(
    unsigned short* __restrict__ kpx, unsigned short* __restrict__ vt16)
{
    int bh = blockIdx.x;
    int t = threadIdx.x;
    for (int pos = NKEY; pos < NKEYPAD; ++pos) {
        unsigned short* row = kpx + ((size_t)bh * NKEYPAD + pos) * XD;
        row[t] = 0;
        row[64 + t] = (t == 56) ? 0x3F80 : 0;
        vt16[((size_t)bh * HD + t) * NKEYPAD + pos] = 0;
    }
}

// ---------------------------------------------------------------------------
// MFMA rel-pos dots -> bf16 Q-ext columns of qpx. blockIdx.z = mode.
// ---------------------------------------------------------------------------
__global__ __launch_bounds__(256) void rel_mfma(
    const unsigned short* __restrict__ qpx, const unsigned short* __restrict__ rh,
    const unsigned short* __restrict__ rw, unsigned short* __restrict__ qpx_out)
{
    __shared__ char bbuf[4096];     // [32 rows][64 bf16], XOR-swizzled
    int X = blockIdx.x;
    int m0 = blockIdx.y * 256;
    int mode = blockIdx.z;
    const unsigned short* rtab = mode ? rw : rh;
    int t = threadIdx.x;
    int wave = t >> 6, lane = t & 63;
    int lm = lane & 15, lkg = lane >> 4;

    {
        int row = t >> 3, c8 = t & 7;
        int4 val = {0, 0, 0, 0};
        if (row < 28) {
            int dh = X - 2 * row + 54;              // in [0, 110)
            val = *reinterpret_cast<const int4*>(rtab + (size_t)dh * HD + c8 * 8);
        }
        *reinterpret_cast<int4*>(&bbuf[row * 128 + ((c8 * 16) ^ ((row & 7) << 4))]) = val;
    }
    __syncthreads();

    int rbase = m0 + wave * 64 + lm;
    f32x4 acc[4][2] = {};
    #pragma unroll
    for (int kc = 0; kc < 2; ++kc) {
        bf16x8 bfrag[2];
        #pragma unroll
        for (int nb = 0; nb < 2; ++nb) {
            int row = nb * 16 + lm;
            bfrag[nb] = *reinterpret_cast<const bf16x8*>(
                &bbuf[row * 128 + (((kc * 4 + lkg) * 16) ^ ((row & 7) << 4))]);
        }
        #pragma unroll
        for (int m = 0; m < 4; ++m) {
            int rho = rbase + m * 16; if (rho > RELROWS - 1) rho = RELROWS - 1;
            int bh = rho / 56, rem = rho % 56;
            int pos1 = (mode == 0) ? X * 56 + rem : rem * 56 + X;
            const unsigned short* qsrc =
                qpx + ((size_t)bh * NTOK + 1 + pos1) * XD + kc * 32 + lkg * 8;
            bf16x8 af = *reinterpret_cast<const bf16x8*>(qsrc);
            acc[m][0] = __builtin_amdgcn_mfma_f32_16x16x32_bf16(af, bfrag[0], acc[m][0], 0, 0, 0);
            acc[m][1] = __builtin_amdgcn_mfma_f32_16x16x32_bf16(af, bfrag[1], acc[m][1], 0, 0, 0);
        }
    }

    #pragma unroll
    for (int m = 0; m < 4; ++m) {
        #pragma unroll
        for (int r = 0; r < 4; ++r) {
            int rho = m0 + wave * 64 + m * 16 + lkg * 4 + r;
            if (rho >= RELROWS) continue;
            int bh = rho / 56, rem = rho % 56;
            int pos1 = (mode == 0) ? X * 56 + rem : rem * 56 + X;
            unsigned short* dst =
                qpx_out + ((size_t)bh * NTOK + 1 + pos1) * XD + 64 + mode * 28;
            dst[lm] = f2bf(acc[m][0][r] * 8.f);             // -> log2e * (q.r)
            if (lm < 12) dst[16 + lm] = f2bf(acc[m][1][r] * 8.f);
        }
    }
}

// ---------------------------------------------------------------------------
// MFMA flash attention, 4 waves x 32 q-rows (QT=128, 256 thr), swapped QK
// (mfma(K,Q): lane holds q=lm, keys lkg*4+r), bias in ext-128 K-dim, 3-stage
// pipeline (counted vmcnt(3), ONE barrier/iter), XCD swizzle, exp2 scores.
// kf/vf LDS reads amortize over 2 q-row-blocks. P round-trip: b64 writes
// (4 consecutive k), lane-linear b128 read. osum partials reduced over lkg
// groups (shfl_xor 16/32) before reciprocal.
// [r14/r16 post-mortems: 2-tile/block (VGPR 104, 1 blk/CU) and 8-wave/block
//  (512 thr, ~1 blk/CU) both regressed -- this 4-wave config is the
//  empirical optimum of the explored space.]
// ---------------------------------------------------------------------------
__global__ __launch_bounds__(256, 3) void attn_mfma(
    const unsigned short* __restrict__ qpx, const unsigned short* __restrict__ kpx,
    const unsigned short* __restrict__ vt, unsigned short* __restrict__ outp)
{
    __shared__ __align__(16) char kbuf[3][8192];   // Kext tile [32][128] bf16
    __shared__ __align__(16) char vbuf[3][4096];   // Vt tile  [64][32]  bf16
    __shared__ __align__(16) char pbuf[4][2048];   // per-wave P [32 q][32 k]

    int bid0 = blockIdx.x;
    int bid = (bid0 & 7) * ((NBH * NQT2) / 8) + (bid0 >> 3);   // 1200 % 8 == 0
    int tile = bid % NQT2;
    int bh = bid / NQT2;
    int head = bh % NHEAD, b = bh / NHEAD;
    int q0 = tile * QT2;
    int t = threadIdx.x;
    int wave = t >> 6, lane = t & 63;
    int lm = lane & 15, lkg = lane >> 4;

    const unsigned short* kb  = kpx + (size_t)bh * NKEYPAD * XD;
    const unsigned short* vtb = vt + (size_t)bh * HD * NKEYPAD;

    // Q fragments: 2 row-blocks x 4 chunks of 32 ext-dims
    bf16x8 qf[2][4] = {};
    #pragma unroll
    for (int rb = 0; rb < 2; ++rb) {
        int qrow = q0 + wave * 32 + rb * 16 + lm;
        if (qrow < NTOK) {
            const unsigned short* qs = qpx + ((size_t)bh * NTOK + qrow) * XD + lkg * 8;
            qf[rb][0] = *reinterpret_cast<const bf16x8*>(qs);
            qf[rb][1] = *reinterpret_cast<const bf16x8*>(qs + 32);
            qf[rb][2] = *reinterpret_cast<const bf16x8*>(qs + 64);
            qf[rb][3] = *reinterpret_cast<const bf16x8*>(qs + 96);
        }
    }

    f32x4 oacc[2][4] = {};
    float osum[2] = {0.f, 0.f};    // partial per lane: q = lm, keys of lkg grp

    // K staging: 2 chunks/thread (rows 0-15, 16-31), pre-swizzled source
    int kr = t >> 4;
    int ks = (t & 15) ^ (kr & 7);
    const unsigned short* kp0 = kb + (size_t)kr * XD + ks * 8;
    const unsigned short* kp1 = kb + (size_t)(kr + 16) * XD + ks * 8;
    int kd0 = t * 16, kd1 = 4096 + t * 16;
    // V staging: 1 chunk/thread
    int vr = t >> 2;
    int vs = (t & 3) ^ ((vr >> 1) & 3);
    const unsigned short* vp0 = vtb + (size_t)vr * NKEYPAD + vs * 8;
    int vd = t * 16;

    const int NT = NKEYPAD / 32;   // 25

    // prologue: stage tiles 0,1 (3 loads per thread per tile)
    gl16(kp0, &kbuf[0][kd0]); gl16(kp1, &kbuf[0][kd1]); gl16(vp0, &vbuf[0][vd]);
    kp0 += 32 * XD; kp1 += 32 * XD; vp0 += 32;
    gl16(kp0, &kbuf[1][kd0]); gl16(kp1, &kbuf[1][kd1]); gl16(vp0, &vbuf[1][vd]);
    kp0 += 32 * XD; kp1 += 32 * XD; vp0 += 32;

    // P write address base: byte(P[q][k]) = (k>>3)*256 + q*16 + (k&7)*2
    int pwbase = lm * 16 + ((lkg & 1) << 3);   // + (nb*2 + (lkg>>1))*256 + rb*1024

    int cur = 0;
    for (int jt = 0; jt < NT; ++jt) {
        if (jt + 1 < NT) asm volatile("s_waitcnt vmcnt(3)" ::: "memory");
        else             asm volatile("s_waitcnt vmcnt(0)" ::: "memory");
        __builtin_amdgcn_s_barrier();   // tile jt fully in LDS

        // stage tile jt+2 into buf[(jt+2)%3] (last read at jt-1, retired)
        if (jt + 2 < NT) {
            int nx = cur + 2; if (nx >= 3) nx -= 3;
            gl16(kp0, &kbuf[nx][kd0]);
            gl16(kp1, &kbuf[nx][kd1]);
            gl16(vp0, &vbuf[nx][vd]);
            kp0 += 32 * XD; kp1 += 32 * XD; vp0 += 32;
        }

        // Swapped QK^T: S[k][q] = mfma(Kext, Qext); kf shared across both rb
        f32x4 a00 = {0.f,0.f,0.f,0.f}, a01 = {0.f,0.f,0.f,0.f};
        f32x4 a10 = {0.f,0.f,0.f,0.f}, a11 = {0.f,0.f,0.f,0.f};
        __builtin_amdgcn_s_setprio(1);
        #pragma unroll
        for (int kc = 0; kc < 4; ++kc) {
            int sl = (kc * 4 + lkg) ^ (lm & 7);
            bf16x8 kf0 = *reinterpret_cast<const bf16x8*>(&kbuf[cur][lm * 256 + sl * 16]);
            bf16x8 kf1 = *reinterpret_cast<const bf16x8*>(&kbuf[cur][(16 + lm) * 256 + sl * 16]);
            a00 = __builtin_amdgcn_mfma_f32_16x16x32_bf16(kf0, qf[0][kc], a00, 0, 0, 0);
            a01 = __builtin_amdgcn_mfma_f32_16x16x32_bf16(kf1, qf[0][kc], a01, 0, 0, 0);
            a10 = __builtin_amdgcn_mfma_f32_16x16x32_bf16(kf0, qf[1][kc], a10, 0, 0, 0);
            a11 = __builtin_amdgcn_mfma_f32_16x16x32_bf16(kf1, qf[1][kc], a11, 0, 0, 0);
        }
        __builtin_amdgcn_s_setprio(0);

        // exp2 + pack pairs + b64 write (4 consecutive k per write)
        #pragma unroll
        for (int rb = 0; rb < 2; ++rb) {
            #pragma unroll
            for (int nb = 0; nb < 2; ++nb) {
                f32x4 a = rb ? (nb ? a11 : a10) : (nb ? a01 : a00);
                float e0, e1, e2, e3;
                asm("v_exp_f32 %0, %1" : "=v"(e0) : "v"(a[0]));
                asm("v_exp_f32 %0, %1" : "=v"(e1) : "v"(a[1]));
                asm("v_exp_f32 %0, %1" : "=v"(e2) : "v"(a[2]));
                asm("v_exp_f32 %0, %1" : "=v"(e3) : "v"(a[3]));
                osum[rb] += (e0 + e1) + (e2 + e3);
                union { float f; unsigned u; } u0, u1, u2, u3;
                u0.f = e0; u1.f = e1; u2.f = e2; u3.f = e3;
                uint2 pk;
                pk.x = (u0.u >> 16) | (u1.u & 0xFFFF0000u);   // k+0, k+1
                pk.y = (u2.u >> 16) | (u3.u & 0xFFFF0000u);   // k+2, k+3
                int addr = (rb << 10) + ((nb * 2 + (lkg >> 1)) << 8) + pwbase;
                *reinterpret_cast<uint2*>(&pbuf[wave][addr]) = pk;
            }
        }

        // PV: O[rb] += P[rb][16x32] * Vt ; pf read is lane-linear (no conflict)
        bf16x8 pf0 = *reinterpret_cast<const bf16x8*>(&pbuf[wave][lane * 16]);
        bf16x8 pf1 = *reinterpret_cast<const bf16x8*>(&pbuf[wave][1024 + lane * 16]);
        __builtin_amdgcn_s_setprio(1);
        #pragma unroll
        for (int db = 0; db < 4; ++db) {
            int row = db * 16 + lm;
            bf16x8 vf = *reinterpret_cast<const bf16x8*>(
                &vbuf[cur][row * 64 + ((lkg ^ ((row >> 1) & 3)) << 4)]);
            oacc[0][db] = __builtin_amdgcn_mfma_f32_16x16x32_bf16(pf0, vf, oacc[0][db], 0, 0, 0);
            oacc[1][db] = __builtin_amdgcn_mfma_f32_16x16x32_bf16(pf1, vf, oacc[1][db], 0, 0, 0);
        }
        __builtin_amdgcn_s_setprio(0);

        cur = (cur == 2) ? 0 : cur + 1;
    }

    // FULL denominator: reduce partials across the 4 lkg groups (bits 4,5),
    // then lane-local reciprocal; broadcast to output layout via shfl.
    #pragma unroll
    for (int rb = 0; rb < 2; ++rb) {
        osum[rb] += __shfl_xor(osum[rb], 16, 64);
        osum[rb] += __shfl_xor(osum[rb], 32, 64);
    }
    float inv[2] = { 1.f / osum[0], 1.f / osum[1] };
    #pragma unroll
    for (int rb = 0; rb < 2; ++rb) {
        #pragma unroll
        for (int r = 0; r < 4; ++r) {
            float invq = __shfl(inv[rb], lkg * 4 + r, 64);   // lane with lm = q
            int qpos = q0 + wave * 32 + rb * 16 + lkg * 4 + r;
            if (qpos >= NTOK) continue;
            unsigned short* orow = outp + ((size_t)b * NTOK + qpos) * DIM + (size_t)head * HD;
            const unsigned short* qres = qpx + ((size_t)bh * NTOK + qpos) * XD;
            #pragma unroll
            for (int db = 0; db < 4; ++db) {
                int d = db * 16 + lm;
                float o = oacc[rb][db][r] * invq;
                if (qpos > 0) o += bf2f(qres[d]) * QUNSCALE;   // residual
                orow[d] = f2bf(o);
            }
        }
    }
}

// ---------------------------------------------------------------------------
extern "C" void kernel_launch(void* const* d_in, const int* in_sizes, int n_in,
                              void* d_out, int out_size, void* d_ws, size_t ws_size,
                              hipStream_t stream) {
    const float* x     = (const float*)d_in[0];
    const float* Wqkv  = (const float*)d_in[1];
    const float* pqw   = (const float*)d_in[2];
    const float* pkw   = (const float*)d_in[3];
    const float* pvw   = (const float*)d_in[4];
    const float* gq    = (const float*)d_in[5];
    const float* bq    = (const float*)d_in[6];
    const float* gk    = (const float*)d_in[7];
    const float* bk    = (const float*)d_in[8];
    const float* gv    = (const float*)d_in[9];
    const float* bv    = (const float*)d_in[10];
    const float* rph   = (const float*)d_in[11];
    const float* rpw   = (const float*)d_in[12];
    const float* Wproj = (const float*)d_in[13];
    const float* bproj = (const float*)d_in[14];

    unsigned short* qkvb  = (unsigned short*)d_ws;                 // [M][2304] bf16
    unsigned short* qpx   = qkvb + (size_t)MROWS * THREE_DIM;      // [48][3137][128]
    unsigned short* kpx   = qpx + (size_t)NBH * NTOK * XD;         // [48][800][128]
    unsigned short* vt16  = kpx + (size_t)NBH * NKEYPAD * XD;      // [48][64][800]
    unsigned short* xbf   = vt16 + (size_t)NBH * HD * NKEYPAD;     // [M][768]
    unsigned short* wqkvt = xbf + (size_t)MROWS * DIM;             // [2304][768]
    unsigned short* wprojt= wqkvt + (size_t)DIM * THREE_DIM;       // [768][768]
    unsigned short* rphb  = wprojt + (size_t)DIM * DIM;            // [111][64]
    unsigned short* rpwb  = rphb + 7104;
    unsigned short* attn_bf = qkvb;            // alias (qkvb dead after pools)

    dim3 blk(256);

    // 0) bf16 conversions (consolidated)
    cvt_bf16<<<2048, blk, 0, stream>>>(x, xbf, (int)((size_t)MROWS * DIM / 4));
    {
        dim3 g(THREE_DIM / 32, DIM / 32, 2);
        transpose_bf16_2<<<g, blk, 0, stream>>>(Wqkv, wqkvt, Wproj, wprojt);
    }
    cvt_rel<<<14, blk, 0, stream>>>(rph, rpw, rphb, rpwb);

    // 1) qkv = x @ Wqkv   (bf16 MFMA 128^2 pipelined, bf16 out)
    {
        dim3 grid(THREE_DIM / 128, (MROWS + 127) / 128);
        gemm_mfma<<<grid, blk, 0, stream>>>(xbf, wqkvt, nullptr, qkvb,
                                            MROWS, THREE_DIM, DIM, 1);
    }

    // 2) pool + LN: q-ext; k-ext + v^T merged; then pad rows
    pool_ln_q<<<NBH * QH, blk, 0, stream>>>(qkvb, pqw, gq, bq, qpx);
    {
        dim3 g(NBH * 28, 2);
        pool_ln_kv<<<g, blk, 0, stream>>>(qkvb, pkw, gk, bk, kpx,
                                          pvw, gv, bv, vt16);
    }
    pad_kv<<<NBH, 64, 0, stream>>>(kpx, vt16);

    // 3) rel-pos dots -> Q-ext columns (bf16, in-place into qpx), both modes
    {
        dim3 g(56, (RELROWS + 255) / 256, 2);
        rel_mfma<<<g, blk, 0, stream>>>(qpx, rphb, rpwb, qpx);
    }

    // 4) MFMA flash attention (bias folded, exp2 scores) -> bf16
    attn_mfma<<<NBH * NQT2, blk, 0, stream>>>(qpx, kpx, vt16, attn_bf);

    // 5) out = attn_out @ Wproj + bproj   (bf16 MFMA, fp32 out)
    {
        dim3 grid(DIM / 128, (MROWS + 127) / 128);
        gemm_mfma<<<grid, blk, 0, stream>>>(attn_bf, wprojt, bproj, d_out,
                                            MROWS, DIM, DIM, 0);
    }
}

// Round 18
// 275.144 us; speedup vs baseline: 1.7662x; 1.0063x over previous
//
#include <hip/hip_runtime.h>
#include <hip/hip_bf16.h>

// Problem constants (fixed by setup_inputs)
#define BATCH 4
#define NTOK 3137        // 1 + 56*56
#define DIM 768
#define NHEAD 12
#define HD 64
#define QH 56
#define QW 56
#define NKEY 785         // 1 + 28*28
#define NKEYPAD 800      // padded key count (25 x 32)
#define THREE_DIM 2304
#define MROWS (BATCH*NTOK)   // 12548
#define QT2 128              // attn q-tile (4 waves x 32 rows)
#define NQT2 25              // ceil(3137/128)
#define NBH 48               // BATCH*NHEAD
#define RELROWS (NBH*56)     // 2688
#define XD 128               // extended head dim (64 q + 28 relh + 28 relw + pad flag)

// exp2 folding: q pre-scale = 0.125 * log2(e); scores come out in log2 units
#define QSCALE 0.1803368801111204f
#define QUNSCALE 5.5451774444795625f   // 1/QSCALE (residual recovery)
#define PADSUP  -43.3f                 // -30 * log2(e)

typedef __attribute__((ext_vector_type(8))) short bf16x8;
typedef __attribute__((ext_vector_type(4))) float f32x4;

__device__ __forceinline__ unsigned short f2bf(float f) {
    union { float f; unsigned u; } v; v.f = f;
    unsigned r = v.u + 0x7FFFu + ((v.u >> 16) & 1u);   // RNE
    return (unsigned short)(r >> 16);
}
__device__ __forceinline__ float bf2f(unsigned short s) {
    union { unsigned u; float f; } v; v.u = (unsigned)s << 16; return v.f;
}

__device__ __forceinline__ void gl16(const void* g, void* l) {
    __builtin_amdgcn_global_load_lds(
        (const __attribute__((address_space(1))) unsigned int*)g,
        (__attribute__((address_space(3))) unsigned int*)l, 16, 0, 0);
}

// ---------------------------------------------------------------------------
// fp32 -> bf16 elementwise (vectorized x4)
// ---------------------------------------------------------------------------
__global__ __launch_bounds__(256) void cvt_bf16(
    const float* __restrict__ in, unsigned short* __restrict__ outp, int n4)
{
    for (int i = blockIdx.x * 256 + threadIdx.x; i < n4; i += gridDim.x * 256) {
        float4 v = reinterpret_cast<const float4*>(in)[i];
        union { unsigned short s[4]; uint2 u; } o;
        o.s[0] = f2bf(v.x); o.s[1] = f2bf(v.y);
        o.s[2] = f2bf(v.z); o.s[3] = f2bf(v.w);
        reinterpret_cast<uint2*>(outp)[i] = o.u;
    }
}

// Both rel tables in one launch (n4 = 1776 each)
__global__ __launch_bounds__(256) void cvt_rel(
    const float* __restrict__ h, const float* __restrict__ w,
    unsigned short* __restrict__ hb, unsigned short* __restrict__ wb)
{
    int i = blockIdx.x * 256 + threadIdx.x;
    const float* src; unsigned short* dst; int j;
    if (i < 1776)      { src = h; dst = hb; j = i; }
    else if (i < 3552) { src = w; dst = wb; j = i - 1776; }
    else return;
    float4 v = reinterpret_cast<const float4*>(src)[j];
    union { unsigned short s[4]; uint2 u; } o;
    o.s[0] = f2bf(v.x); o.s[1] = f2bf(v.y);
    o.s[2] = f2bf(v.z); o.s[3] = f2bf(v.w);
    reinterpret_cast<uint2*>(dst)[j] = o.u;
}

// ---------------------------------------------------------------------------
// W[K][N] fp32 -> Wt[N][K] bf16; z=0: Wqkv(768x2304), z=1: Wproj(768x768)
// ---------------------------------------------------------------------------
__global__ __launch_bounds__(256) void transpose_bf16_2(
    const float* __restrict__ W0, unsigned short* __restrict__ Wt0,
    const float* __restrict__ W1, unsigned short* __restrict__ Wt1)
{
    const float* W; unsigned short* Wt; int N;
    if (blockIdx.z == 0) { W = W0; Wt = Wt0; N = THREE_DIM; }
    else {
        if (blockIdx.x >= DIM / 32) return;
        W = W1; Wt = Wt1; N = DIM;
    }
    const int K = DIM;
    __shared__ float tile[32][33];
    int k0 = blockIdx.y * 32, n0 = blockIdx.x * 32;
    int t = threadIdx.x;
    int r = t >> 5, c = t & 31;
    #pragma unroll
    for (int p = 0; p < 4; ++p)
        tile[r + p * 8][c] = W[(size_t)(k0 + r + p * 8) * N + n0 + c];
    __syncthreads();
    #pragma unroll
    for (int p = 0; p < 4; ++p)
        Wt[(size_t)(n0 + r + p * 8) * K + k0 + c] = f2bf(tile[c][r + p * 8]);
}

// ---------------------------------------------------------------------------
// bf16 MFMA GEMM, 128x128 tile, 4 waves (2x2), BK=32, 3-stage LDS pipeline
// (48 KB), counted vmcnt(4), ONE top barrier per iter. setprio around MFMA.
// ---------------------------------------------------------------------------
__global__ __launch_bounds__(256, 3) void gemm_mfma(
    const unsigned short* __restrict__ A, const unsigned short* __restrict__ Bt,
    const float* __restrict__ bias, void* __restrict__ C,
    int M, int N, int K, int out_bf16)
{
    __shared__ __align__(16) char lds[49152];   // 3 stages x (A 8K | B 8K)
    int t = threadIdx.x;
    int wave = t >> 6, lane = t & 63;
    int lm = lane & 15, lkg = lane >> 4;
    int wr = wave >> 1, wc = wave & 1;

    // bijective XCD remap (m204)
    int gx = gridDim.x;
    int nwg = gx * gridDim.y;
    int lin = blockIdx.y * gx + blockIdx.x;
    int qq = nwg >> 3, rr = nwg & 7;
    int xcd = lin & 7, idx = lin >> 3;
    int newlin = (xcd < rr ? xcd * (qq + 1) : rr * (qq + 1) + (xcd - rr) * qq) + idx;
    int m0 = (newlin / gx) * 128, n0 = (newlin % gx) * 128;

    // staging roles: 2 chunks per matrix per thread, pre-swizzled source
    const unsigned short *gpa0, *gpa1, *gpb0, *gpb1;
    int la0, la1, lb0, lb1;
    {
        int o0 = t * 16, o1 = 4096 + t * 16;
        int r0 = o0 >> 6, s0 = ((o0 >> 4) & 3) ^ ((r0 >> 1) & 3);
        int r1 = o1 >> 6, s1 = ((o1 >> 4) & 3) ^ ((r1 >> 1) & 3);
        int ar0 = m0 + r0; if (ar0 >= M) ar0 = M - 1;
        int ar1 = m0 + r1; if (ar1 >= M) ar1 = M - 1;
        gpa0 = A + (size_t)ar0 * K + s0 * 8;  la0 = o0;
        gpa1 = A + (size_t)ar1 * K + s1 * 8;  la1 = o1;
        gpb0 = Bt + (size_t)(n0 + r0) * K + s0 * 8;  lb0 = 8192 + o0;
        gpb1 = Bt + (size_t)(n0 + r1) * K + s1 * 8;  lb1 = 8192 + o1;
    }

    f32x4 acc[4][4] = {};
    const int nt = K >> 5;      // 24

    // prologue: stage tiles 0 (buf0) and 1 (buf1); 8 loads stay in flight
    gl16(gpa0, &lds[la0]); gl16(gpa1, &lds[la1]);
    gl16(gpb0, &lds[lb0]); gl16(gpb1, &lds[lb1]);
    gpa0 += 32; gpa1 += 32; gpb0 += 32; gpb1 += 32;
    gl16(gpa0, &lds[16384 + la0]); gl16(gpa1, &lds[16384 + la1]);
    gl16(gpb0, &lds[16384 + lb0]); gl16(gpb1, &lds[16384 + lb1]);
    gpa0 += 32; gpa1 += 32; gpb0 += 32; gpb1 += 32;

    int cur = 0;
    for (int tt = 0; tt < nt; ++tt) {
        if (tt + 1 < nt) asm volatile("s_waitcnt vmcnt(4)" ::: "memory");
        else             asm volatile("s_waitcnt vmcnt(0)" ::: "memory");
        __builtin_amdgcn_s_barrier();   // tile tt fully in LDS (all waves)

        // stage tile tt+2 -> buf[(cur+2)%3] (its readers retired at tt-1)
        if (tt + 2 < nt) {
            int nx = cur + 2; if (nx >= 3) nx -= 3;
            char* nb = &lds[nx << 14];
            gl16(gpa0, nb + la0); gl16(gpa1, nb + la1);
            gl16(gpb0, nb + lb0); gl16(gpb1, nb + lb1);
            gpa0 += 32; gpa1 += 32; gpb0 += 32; gpb1 += 32;
        }

        char* base = &lds[cur << 14];
        bf16x8 af[4], bfr[4];
        #pragma unroll
        for (int m = 0; m < 4; ++m) {
            int row = wr * 64 + m * 16 + lm;
            af[m] = *reinterpret_cast<const bf16x8*>(
                base + row * 64 + ((lkg ^ ((row >> 1) & 3)) << 4));
        }
        #pragma unroll
        for (int n = 0; n < 4; ++n) {
            int row = wc * 64 + n * 16 + lm;
            bfr[n] = *reinterpret_cast<const bf16x8*>(
                base + 8192 + row * 64 + ((lkg ^ ((row >> 1) & 3)) << 4));
        }
        __builtin_amdgcn_s_setprio(1);
        #pragma unroll
        for (int m = 0; m < 4; ++m)
            #pragma unroll
            for (int n = 0; n < 4; ++n)
                acc[m][n] = __builtin_amdgcn_mfma_f32_16x16x32_bf16(
                    af[m], bfr[n], acc[m][n], 0, 0, 0);
        __builtin_amdgcn_s_setprio(0);

        cur = (cur == 2) ? 0 : cur + 1;
    }

    // epilogue: row-contiguous store order (n innermost => full 128B lines)
    float bv[4];
    #pragma unroll
    for (int n = 0; n < 4; ++n)
        bv[n] = bias ? bias[n0 + wc * 64 + n * 16 + lm] : 0.f;
    #pragma unroll
    for (int m = 0; m < 4; ++m) {
        #pragma unroll
        for (int r = 0; r < 4; ++r) {
            int row = m0 + wr * 64 + m * 16 + lkg * 4 + r;
            if (row >= M) continue;
            #pragma unroll
            for (int n = 0; n < 4; ++n) {
                int col = n0 + wc * 64 + n * 16 + lm;
                float o = acc[m][n][r] + bv[n];
                if (out_bf16)
                    ((unsigned short*)C)[(size_t)row * N + col] = f2bf(o);
                else
                    ((float*)C)[(size_t)row * N + col] = o;
            }
        }
    }
}

// ---------------------------------------------------------------------------
// Row-tiled depthwise 3x3 pool + LayerNorm (shared body).
// mode 3: q-ext [bh][pos][128] (q*QSCALE, ext zeros, [120]=PADSUP)
// mode 1: k-ext [bh][pos][128] (k, onehot(kh)/onehot(kw))
// mode 2: v^T   [bh][64][NKEYPAD]
// ---------------------------------------------------------------------------
__device__ __forceinline__ void pool_body(
    const unsigned short* src, const float* w, const float* g,
    const float* beta, unsigned short* outp, int bh, int orow,
    int stride, int OW, int mode, unsigned short* ibuf,
    int t, int wave, int lane)
{
    for (int i = t; i < 3 * 56 * 32; i += 256) {
        int pair = i >> 5, off = i & 31;
        int r = pair / 56, iw = pair % 56;
        int ih = orow * stride + r - 1;
        unsigned v = 0;
        if (ih >= 0 && ih < QH)
            v = *reinterpret_cast<const unsigned*>(
                src + (size_t)(1 + ih * QW + iw) * THREE_DIM + off * 2);
        *reinterpret_cast<unsigned*>(&ibuf[pair * 64 + off * 2]) = v;
    }

    float wreg[9];
    #pragma unroll
    for (int k = 0; k < 9; ++k) wreg[k] = w[lane * 9 + k];
    float gl = g[lane], bl = beta[lane];
    __syncthreads();

    int ntask = OW + ((orow == 0) ? 1 : 0);    // extra task: cls (pos 0)
    for (int task = wave; task < ntask; task += 4) {
        float val;
        int pos;
        if (task == OW) {                      // cls token
            val = bf2f(src[lane]);
            pos = 0;
        } else {
            int ow = task;
            float acc = 0.f;
            #pragma unroll
            for (int r = 0; r < 3; ++r) {
                #pragma unroll
                for (int c = 0; c < 3; ++c) {
                    int iwc = ow * stride + c - 1;
                    if (iwc < 0 || iwc >= QW) continue;
                    acc += bf2f(ibuf[(r * 56 + iwc) * 64 + lane]) * wreg[r * 3 + c];
                }
            }
            val = acc;
            pos = 1 + orow * OW + ow;
        }

        float mu = val;
        #pragma unroll
        for (int off = 32; off > 0; off >>= 1) mu += __shfl_xor(mu, off, 64);
        mu *= (1.f / 64.f);
        float dv = val - mu;
        float var = dv * dv;
        #pragma unroll
        for (int off = 32; off > 0; off >>= 1) var += __shfl_xor(var, off, 64);
        var *= (1.f / 64.f);
        float o = dv * rsqrtf(var + 1e-5f) * gl + bl;

        if (mode == 3) {
            unsigned short* row = outp + ((size_t)bh * NTOK + pos) * XD;
            row[lane] = f2bf(o * QSCALE);
            row[64 + lane] = (lane == 56) ? f2bf(PADSUP) : 0;
        } else if (mode == 1) {
            unsigned short* row = outp + ((size_t)bh * NKEYPAD + pos) * XD;
            row[lane] = f2bf(o);
            unsigned short ext = 0;
            if (pos > 0) {
                int kh = (pos - 1) / 28, kw = (pos - 1) % 28;
                if ((lane < 28 && lane == kh) ||
                    (lane >= 28 && lane < 56 && lane - 28 == kw))
                    ext = 0x3F80;   // 1.0 bf16
            }
            row[64 + lane] = ext;
        } else {
            outp[((size_t)bh * HD + lane) * NKEYPAD + pos] = f2bf(o);
        }
    }
}

__global__ __launch_bounds__(256) void pool_ln_q(
    const unsigned short* __restrict__ qkvb, const float* __restrict__ w,
    const float* __restrict__ g, const float* __restrict__ beta,
    unsigned short* __restrict__ outp)
{
    __shared__ unsigned short ibuf[3 * 56 * 64];
    int bid = blockIdx.x;
    int orow = bid % QH;
    int bh = bid / QH;
    int head = bh % NHEAD, b = bh / NHEAD;
    const unsigned short* src =
        qkvb + (size_t)b * NTOK * THREE_DIM + (size_t)head * HD;
    pool_body(src, w, g, beta, outp, bh, orow, 1, QW, 3, ibuf,
              threadIdx.x, threadIdx.x >> 6, threadIdx.x & 63);
}

// k (y=0) and v (y=1) pools in one launch
__global__ __launch_bounds__(256) void pool_ln_kv(
    const unsigned short* __restrict__ qkvb,
    const float* __restrict__ wk, const float* __restrict__ gk,
    const float* __restrict__ bk, unsigned short* __restrict__ kpx,
    const float* __restrict__ wv, const float* __restrict__ gv,
    const float* __restrict__ bv, unsigned short* __restrict__ vt16)
{
    __shared__ unsigned short ibuf[3 * 56 * 64];
    int bid = blockIdx.x;
    int orow = bid % 28;
    int bh = bid / 28;
    int head = bh % NHEAD, b = bh / NHEAD;
    int isv = blockIdx.y;
    const unsigned short* src = qkvb + (size_t)b * NTOK * THREE_DIM
        + (size_t)(isv ? 2 : 1) * DIM + (size_t)head * HD;
    if (isv)
        pool_body(src, wv, gv, bv, vt16, bh, orow, 2, 28, 2, ibuf,
                  threadIdx.x, threadIdx.x >> 6, threadIdx.x & 63);
    else
        pool_body(src, wk, gk, bk, kpx, bh, orow, 2, 28, 1, ibuf,
                  threadIdx.x, threadIdx.x >> 6, threadIdx.x & 63);
}

// ---------------------------------------------------------------------------
// Pad rows (785..799): k-ext rows = pad-flag onehot; v^T pad cols = 0.
// ---------------------------------------------------------------------------
__global__ __launch_bounds__(64) void pad_kv(
    unsigned short* __restrict__ kpx, unsigned short* __restrict__ vt16)
{
    int bh = blockIdx.x;
    int t = threadIdx.x;
    for (int pos = NKEY; pos < NKEYPAD; ++pos) {
        unsigned short* row = kpx + ((size_t)bh * NKEYPAD + pos) * XD;
        row[t] = 0;
        row[64 + t] = (t == 56) ? 0x3F80 : 0;
        vt16[((size_t)bh * HD + t) * NKEYPAD + pos] = 0;
    }
}

// ---------------------------------------------------------------------------
// MFMA rel-pos dots -> bf16 Q-ext columns of qpx. blockIdx.z = mode.
// ---------------------------------------------------------------------------
__global__ __launch_bounds__(256) void rel_mfma(
    const unsigned short* __restrict__ qpx, const unsigned short* __restrict__ rh,
    const unsigned short* __restrict__ rw, unsigned short* __restrict__ qpx_out)
{
    __shared__ char bbuf[4096];     // [32 rows][64 bf16], XOR-swizzled
    int X = blockIdx.x;
    int m0 = blockIdx.y * 256;
    int mode = blockIdx.z;
    const unsigned short* rtab = mode ? rw : rh;
    int t = threadIdx.x;
    int wave = t >> 6, lane = t & 63;
    int lm = lane & 15, lkg = lane >> 4;

    {
        int row = t >> 3, c8 = t & 7;
        int4 val = {0, 0, 0, 0};
        if (row < 28) {
            int dh = X - 2 * row + 54;              // in [0, 110)
            val = *reinterpret_cast<const int4*>(rtab + (size_t)dh * HD + c8 * 8);
        }
        *reinterpret_cast<int4*>(&bbuf[row * 128 + ((c8 * 16) ^ ((row & 7) << 4))]) = val;
    }
    __syncthreads();

    int rbase = m0 + wave * 64 + lm;
    f32x4 acc[4][2] = {};
    #pragma unroll
    for (int kc = 0; kc < 2; ++kc) {
        bf16x8 bfrag[2];
        #pragma unroll
        for (int nb = 0; nb < 2; ++nb) {
            int row = nb * 16 + lm;
            bfrag[nb] = *reinterpret_cast<const bf16x8*>(
                &bbuf[row * 128 + (((kc * 4 + lkg) * 16) ^ ((row & 7) << 4))]);
        }
        #pragma unroll
        for (int m = 0; m < 4; ++m) {
            int rho = rbase + m * 16; if (rho > RELROWS - 1) rho = RELROWS - 1;
            int bh = rho / 56, rem = rho % 56;
            int pos1 = (mode == 0) ? X * 56 + rem : rem * 56 + X;
            const unsigned short* qsrc =
                qpx + ((size_t)bh * NTOK + 1 + pos1) * XD + kc * 32 + lkg * 8;
            bf16x8 af = *reinterpret_cast<const bf16x8*>(qsrc);
            acc[m][0] = __builtin_amdgcn_mfma_f32_16x16x32_bf16(af, bfrag[0], acc[m][0], 0, 0, 0);
            acc[m][1] = __builtin_amdgcn_mfma_f32_16x16x32_bf16(af, bfrag[1], acc[m][1], 0, 0, 0);
        }
    }

    #pragma unroll
    for (int m = 0; m < 4; ++m) {
        #pragma unroll
        for (int r = 0; r < 4; ++r) {
            int rho = m0 + wave * 64 + m * 16 + lkg * 4 + r;
            if (rho >= RELROWS) continue;
            int bh = rho / 56, rem = rho % 56;
            int pos1 = (mode == 0) ? X * 56 + rem : rem * 56 + X;
            unsigned short* dst =
                qpx_out + ((size_t)bh * NTOK + 1 + pos1) * XD + 64 + mode * 28;
            dst[lm] = f2bf(acc[m][0][r] * 8.f);             // -> log2e * (q.r)
            if (lm < 12) dst[16 + lm] = f2bf(acc[m][1][r] * 8.f);
        }
    }
}

// ---------------------------------------------------------------------------
// MFMA flash attention, 4 waves x 32 q-rows (QT=128, 256 thr), swapped QK
// (mfma(K,Q): lane holds q=lm, keys lkg*4+r), bias in ext-128 K-dim,
// 2-STAGE pipeline (32 KB LDS exactly -> 5 blocks/CU, +66% occupancy vs
// r13's 3-stage/45KB/3-blocks). Stage for jt+1 issued AFTER the barrier
// (2-buffer WAR safety) and lands during this iteration's compute; the
// pre-barrier wait is vmcnt(0) but the loads had a full compute phase.
// XCD swizzle, exp2 scores, b64 P-writes, lane-linear P-read, lkg-group
// reduced softmax denominators.
// ---------------------------------------------------------------------------
__global__ __launch_bounds__(256, 3) void attn_mfma(
    const unsigned short* __restrict__ qpx, const unsigned short* __restrict__ kpx,
    const unsigned short* __restrict__ vt, unsigned short* __restrict__ outp)
{
    __shared__ __align__(16) char kbuf[2][8192];   // Kext tile [32][128] bf16
    __shared__ __align__(16) char vbuf[2][4096];   // Vt tile  [64][32]  bf16
    __shared__ __align__(16) char pbuf[4][2048];   // per-wave P [32 q][32 k]

    int bid0 = blockIdx.x;
    int bid = (bid0 & 7) * ((NBH * NQT2) / 8) + (bid0 >> 3);   // 1200 % 8 == 0
    int tile = bid % NQT2;
    int bh = bid / NQT2;
    int head = bh % NHEAD, b = bh / NHEAD;
    int q0 = tile * QT2;
    int t = threadIdx.x;
    int wave = t >> 6, lane = t & 63;
    int lm = lane & 15, lkg = lane >> 4;

    const unsigned short* kb  = kpx + (size_t)bh * NKEYPAD * XD;
    const unsigned short* vtb = vt + (size_t)bh * HD * NKEYPAD;

    // Q fragments: 2 row-blocks x 4 chunks of 32 ext-dims
    bf16x8 qf[2][4] = {};
    #pragma unroll
    for (int rb = 0; rb < 2; ++rb) {
        int qrow = q0 + wave * 32 + rb * 16 + lm;
        if (qrow < NTOK) {
            const unsigned short* qs = qpx + ((size_t)bh * NTOK + qrow) * XD + lkg * 8;
            qf[rb][0] = *reinterpret_cast<const bf16x8*>(qs);
            qf[rb][1] = *reinterpret_cast<const bf16x8*>(qs + 32);
            qf[rb][2] = *reinterpret_cast<const bf16x8*>(qs + 64);
            qf[rb][3] = *reinterpret_cast<const bf16x8*>(qs + 96);
        }
    }

    f32x4 oacc[2][4] = {};
    float osum[2] = {0.f, 0.f};    // partial per lane: q = lm, keys of lkg grp

    // K staging: 2 chunks/thread (rows 0-15, 16-31), pre-swizzled source
    int kr = t >> 4;
    int ks = (t & 15) ^ (kr & 7);
    const unsigned short* kp0 = kb + (size_t)kr * XD + ks * 8;
    const unsigned short* kp1 = kb + (size_t)(kr + 16) * XD + ks * 8;
    int kd0 = t * 16, kd1 = 4096 + t * 16;
    // V staging: 1 chunk/thread
    int vr = t >> 2;
    int vs = (t & 3) ^ ((vr >> 1) & 3);
    const unsigned short* vp0 = vtb + (size_t)vr * NKEYPAD + vs * 8;
    int vd = t * 16;

    const int NT = NKEYPAD / 32;   // 25

    // prologue: stage tile 0 into buf 0 (3 loads)
    gl16(kp0, &kbuf[0][kd0]); gl16(kp1, &kbuf[0][kd1]); gl16(vp0, &vbuf[0][vd]);
    kp0 += 32 * XD; kp1 += 32 * XD; vp0 += 32;

    // P write address base: byte(P[q][k]) = (k>>3)*256 + q*16 + (k&7)*2
    int pwbase = lm * 16 + ((lkg & 1) << 3);   // + (nb*2 + (lkg>>1))*256 + rb*1024

    int cur = 0;
    for (int jt = 0; jt < NT; ++jt) {
        // only tile jt's 3 loads are outstanding here; they had the whole
        // previous compute phase to land.
        asm volatile("s_waitcnt vmcnt(0)" ::: "memory");
        __builtin_amdgcn_s_barrier();   // tile jt in LDS; prev reads retired

        // stage tile jt+1 into buf[cur^1] (WAR-safe: post-barrier);
        // overlaps this iteration's compute.
        if (jt + 1 < NT) {
            gl16(kp0, &kbuf[cur ^ 1][kd0]);
            gl16(kp1, &kbuf[cur ^ 1][kd1]);
            gl16(vp0, &vbuf[cur ^ 1][vd]);
            kp0 += 32 * XD; kp1 += 32 * XD; vp0 += 32;
        }

        // Swapped QK^T: S[k][q] = mfma(Kext, Qext); kf shared across both rb
        f32x4 a00 = {0.f,0.f,0.f,0.f}, a01 = {0.f,0.f,0.f,0.f};
        f32x4 a10 = {0.f,0.f,0.f,0.f}, a11 = {0.f,0.f,0.f,0.f};
        __builtin_amdgcn_s_setprio(1);
        #pragma unroll
        for (int kc = 0; kc < 4; ++kc) {
            int sl = (kc * 4 + lkg) ^ (lm & 7);
            bf16x8 kf0 = *reinterpret_cast<const bf16x8*>(&kbuf[cur][lm * 256 + sl * 16]);
            bf16x8 kf1 = *reinterpret_cast<const bf16x8*>(&kbuf[cur][(16 + lm) * 256 + sl * 16]);
            a00 = __builtin_amdgcn_mfma_f32_16x16x32_bf16(kf0, qf[0][kc], a00, 0, 0, 0);
            a01 = __builtin_amdgcn_mfma_f32_16x16x32_bf16(kf1, qf[0][kc], a01, 0, 0, 0);
            a10 = __builtin_amdgcn_mfma_f32_16x16x32_bf16(kf0, qf[1][kc], a10, 0, 0, 0);
            a11 = __builtin_amdgcn_mfma_f32_16x16x32_bf16(kf1, qf[1][kc], a11, 0, 0, 0);
        }
        __builtin_amdgcn_s_setprio(0);

        // exp2 + pack pairs + b64 write (4 consecutive k per write)
        #pragma unroll
        for (int rb = 0; rb < 2; ++rb) {
            #pragma unroll
            for (int nb = 0; nb < 2; ++nb) {
                f32x4 a = rb ? (nb ? a11 : a10) : (nb ? a01 : a00);
                float e0, e1, e2, e3;
                asm("v_exp_f32 %0, %1" : "=v"(e0) : "v"(a[0]));
                asm("v_exp_f32 %0, %1" : "=v"(e1) : "v"(a[1]));
                asm("v_exp_f32 %0, %1" : "=v"(e2) : "v"(a[2]));
                asm("v_exp_f32 %0, %1" : "=v"(e3) : "v"(a[3]));
                osum[rb] += (e0 + e1) + (e2 + e3);
                union { float f; unsigned u; } u0, u1, u2, u3;
                u0.f = e0; u1.f = e1; u2.f = e2; u3.f = e3;
                uint2 pk;
                pk.x = (u0.u >> 16) | (u1.u & 0xFFFF0000u);   // k+0, k+1
                pk.y = (u2.u >> 16) | (u3.u & 0xFFFF0000u);   // k+2, k+3
                int addr = (rb << 10) + ((nb * 2 + (lkg >> 1)) << 8) + pwbase;
                *reinterpret_cast<uint2*>(&pbuf[wave][addr]) = pk;
            }
        }

        // PV: O[rb] += P[rb][16x32] * Vt ; pf read is lane-linear (no conflict)
        bf16x8 pf0 = *reinterpret_cast<const bf16x8*>(&pbuf[wave][lane * 16]);
        bf16x8 pf1 = *reinterpret_cast<const bf16x8*>(&pbuf[wave][1024 + lane * 16]);
        __builtin_amdgcn_s_setprio(1);
        #pragma unroll
        for (int db = 0; db < 4; ++db) {
            int row = db * 16 + lm;
            bf16x8 vf = *reinterpret_cast<const bf16x8*>(
                &vbuf[cur][row * 64 + ((lkg ^ ((row >> 1) & 3)) << 4)]);
            oacc[0][db] = __builtin_amdgcn_mfma_f32_16x16x32_bf16(pf0, vf, oacc[0][db], 0, 0, 0);
            oacc[1][db] = __builtin_amdgcn_mfma_f32_16x16x32_bf16(pf1, vf, oacc[1][db], 0, 0, 0);
        }
        __builtin_amdgcn_s_setprio(0);

        cur ^= 1;
    }

    // FULL denominator: reduce partials across the 4 lkg groups (bits 4,5),
    // then lane-local reciprocal; broadcast to output layout via shfl.
    #pragma unroll
    for (int rb = 0; rb < 2; ++rb) {
        osum[rb] += __shfl_xor(osum[rb], 16, 64);
        osum[rb] += __shfl_xor(osum[rb], 32, 64);
    }
    float inv[2] = { 1.f / osum[0], 1.f / osum[1] };
    #pragma unroll
    for (int rb = 0; rb < 2; ++rb) {
        #pragma unroll
        for (int r = 0; r < 4; ++r) {
            float invq = __shfl(inv[rb], lkg * 4 + r, 64);   // lane with lm = q
            int qpos = q0 + wave * 32 + rb * 16 + lkg * 4 + r;
            if (qpos >= NTOK) continue;
            unsigned short* orow = outp + ((size_t)b * NTOK + qpos) * DIM + (size_t)head * HD;
            const unsigned short* qres = qpx + ((size_t)bh * NTOK + qpos) * XD;
            #pragma unroll
            for (int db = 0; db < 4; ++db) {
                int d = db * 16 + lm;
                float o = oacc[rb][db][r] * invq;
                if (qpos > 0) o += bf2f(qres[d]) * QUNSCALE;   // residual
                orow[d] = f2bf(o);
            }
        }
    }
}

// ---------------------------------------------------------------------------
extern "C" void kernel_launch(void* const* d_in, const int* in_sizes, int n_in,
                              void* d_out, int out_size, void* d_ws, size_t ws_size,
                              hipStream_t stream) {
    const float* x     = (const float*)d_in[0];
    const float* Wqkv  = (const float*)d_in[1];
    const float* pqw   = (const float*)d_in[2];
    const float* pkw   = (const float*)d_in[3];
    const float* pvw   = (const float*)d_in[4];
    const float* gq    = (const float*)d_in[5];
    const float* bq    = (const float*)d_in[6];
    const float* gk    = (const float*)d_in[7];
    const float* bk    = (const float*)d_in[8];
    const float* gv    = (const float*)d_in[9];
    const float* bv    = (const float*)d_in[10];
    const float* rph   = (const float*)d_in[11];
    const float* rpw   = (const float*)d_in[12];
    const float* Wproj = (const float*)d_in[13];
    const float* bproj = (const float*)d_in[14];

    unsigned short* qkvb  = (unsigned short*)d_ws;                 // [M][2304] bf16
    unsigned short* qpx   = qkvb + (size_t)MROWS * THREE_DIM;      // [48][3137][128]
    unsigned short* kpx   = qpx + (size_t)NBH * NTOK * XD;         // [48][800][128]
    unsigned short* vt16  = kpx + (size_t)NBH * NKEYPAD * XD;      // [48][64][800]
    unsigned short* xbf   = vt16 + (size_t)NBH * HD * NKEYPAD;     // [M][768]
    unsigned short* wqkvt = xbf + (size_t)MROWS * DIM;             // [2304][768]
    unsigned short* wprojt= wqkvt + (size_t)DIM * THREE_DIM;       // [768][768]
    unsigned short* rphb  = wprojt + (size_t)DIM * DIM;            // [111][64]
    unsigned short* rpwb  = rphb + 7104;
    unsigned short* attn_bf = qkvb;            // alias (qkvb dead after pools)

    dim3 blk(256);

    // 0) bf16 conversions (consolidated)
    cvt_bf16<<<2048, blk, 0, stream>>>(x, xbf, (int)((size_t)MROWS * DIM / 4));
    {
        dim3 g(THREE_DIM / 32, DIM / 32, 2);
        transpose_bf16_2<<<g, blk, 0, stream>>>(Wqkv, wqkvt, Wproj, wprojt);
    }
    cvt_rel<<<14, blk, 0, stream>>>(rph, rpw, rphb, rpwb);

    // 1) qkv = x @ Wqkv   (bf16 MFMA 128^2 pipelined, bf16 out)
    {
        dim3 grid(THREE_DIM / 128, (MROWS + 127) / 128);
        gemm_mfma<<<grid, blk, 0, stream>>>(xbf, wqkvt, nullptr, qkvb,
                                            MROWS, THREE_DIM, DIM, 1);
    }

    // 2) pool + LN: q-ext; k-ext + v^T merged; then pad rows
    pool_ln_q<<<NBH * QH, blk, 0, stream>>>(qkvb, pqw, gq, bq, qpx);
    {
        dim3 g(NBH * 28, 2);
        pool_ln_kv<<<g, blk, 0, stream>>>(qkvb, pkw, gk, bk, kpx,
                                          pvw, gv, bv, vt16);
    }
    pad_kv<<<NBH, 64, 0, stream>>>(kpx, vt16);

    // 3) rel-pos dots -> Q-ext columns (bf16, in-place into qpx), both modes
    {
        dim3 g(56, (RELROWS + 255) / 256, 2);
        rel_mfma<<<g, blk, 0, stream>>>(qpx, rphb, rpwb, qpx);
    }

    // 4) MFMA flash attention (bias folded, exp2 scores, 2-stage/32KB)
    attn_mfma<<<NBH * NQT2, blk, 0, stream>>>(qpx, kpx, vt16, attn_bf);

    // 5) out = attn_out @ Wproj + bproj   (bf16 MFMA, fp32 out)
    {
        dim3 grid(DIM / 128, (MROWS + 127) / 128);
        gemm_mfma<<<grid, blk, 0, stream>>>(attn_bf, wprojt, bproj, d_out,
                                            MROWS, DIM, DIM, 0);
    }
}

// Round 19
// 271.222 us; speedup vs baseline: 1.7918x; 1.0145x over previous
//
#include <hip/hip_runtime.h>
#include <hip/hip_bf16.h>

// Problem constants (fixed by setup_inputs)
#define BATCH 4
#define NTOK 3137        // 1 + 56*56
#define DIM 768
#define NHEAD 12
#define HD 64
#define QH 56
#define QW 56
#define NKEY 785         // 1 + 28*28
#define NKEYPAD 800      // padded key count (25 x 32)
#define THREE_DIM 2304
#define MROWS (BATCH*NTOK)   // 12548
#define QT2 128              // attn q-tile (4 waves x 32 rows)
#define NQT2 25              // ceil(3137/128)
#define NBH 48               // BATCH*NHEAD
#define RELROWS (NBH*56)     // 2688
#define XD 128               // extended head dim (64 q + 28 relh + 28 relw + pad flag)

// exp2 folding: q pre-scale = 0.125 * log2(e); scores come out in log2 units
#define QSCALE 0.1803368801111204f
#define QUNSCALE 5.5451774444795625f   // 1/QSCALE (residual recovery)
#define PADSUP  -43.3f                 // -30 * log2(e)

typedef __attribute__((ext_vector_type(8))) short bf16x8;
typedef __attribute__((ext_vector_type(4))) float f32x4;

__device__ __forceinline__ unsigned short f2bf(float f) {
    union { float f; unsigned u; } v; v.f = f;
    unsigned r = v.u + 0x7FFFu + ((v.u >> 16) & 1u);   // RNE
    return (unsigned short)(r >> 16);
}
__device__ __forceinline__ float bf2f(unsigned short s) {
    union { unsigned u; float f; } v; v.u = (unsigned)s << 16; return v.f;
}

__device__ __forceinline__ void gl16(const void* g, void* l) {
    __builtin_amdgcn_global_load_lds(
        (const __attribute__((address_space(1))) unsigned int*)g,
        (__attribute__((address_space(3))) unsigned int*)l, 16, 0, 0);
}

// ---------------------------------------------------------------------------
// fp32 -> bf16 elementwise (vectorized x4)
// ---------------------------------------------------------------------------
__global__ __launch_bounds__(256) void cvt_bf16(
    const float* __restrict__ in, unsigned short* __restrict__ outp, int n4)
{
    for (int i = blockIdx.x * 256 + threadIdx.x; i < n4; i += gridDim.x * 256) {
        float4 v = reinterpret_cast<const float4*>(in)[i];
        union { unsigned short s[4]; uint2 u; } o;
        o.s[0] = f2bf(v.x); o.s[1] = f2bf(v.y);
        o.s[2] = f2bf(v.z); o.s[3] = f2bf(v.w);
        reinterpret_cast<uint2*>(outp)[i] = o.u;
    }
}

// ---------------------------------------------------------------------------
// z=0: Wqkv(768x2304) transpose->bf16; z=1: Wproj(768x768) transpose->bf16;
// z=2: rel tables fp32->bf16 (both, 3552 float4 chunks total).
// ---------------------------------------------------------------------------
__global__ __launch_bounds__(256) void transpose_cvt(
    const float* __restrict__ W0, unsigned short* __restrict__ Wt0,
    const float* __restrict__ W1, unsigned short* __restrict__ Wt1,
    const float* __restrict__ rh, const float* __restrict__ rw,
    unsigned short* __restrict__ rhb, unsigned short* __restrict__ rwb)
{
    int t = threadIdx.x;
    if (blockIdx.z == 2) {
        int idx = blockIdx.y * gridDim.x + blockIdx.x;
        if (idx >= 14) return;
        int i = idx * 256 + t;
        const float* src; unsigned short* dst; int j;
        if (i < 1776)      { src = rh; dst = rhb; j = i; }
        else if (i < 3552) { src = rw; dst = rwb; j = i - 1776; }
        else return;
        float4 v = reinterpret_cast<const float4*>(src)[j];
        union { unsigned short s[4]; uint2 u; } o;
        o.s[0] = f2bf(v.x); o.s[1] = f2bf(v.y);
        o.s[2] = f2bf(v.z); o.s[3] = f2bf(v.w);
        reinterpret_cast<uint2*>(dst)[j] = o.u;
        return;
    }
    const float* W; unsigned short* Wt; int N;
    if (blockIdx.z == 0) { W = W0; Wt = Wt0; N = THREE_DIM; }
    else {
        if (blockIdx.x >= DIM / 32) return;
        W = W1; Wt = Wt1; N = DIM;
    }
    const int K = DIM;
    __shared__ float tile[32][33];
    int k0 = blockIdx.y * 32, n0 = blockIdx.x * 32;
    int r = t >> 5, c = t & 31;
    #pragma unroll
    for (int p = 0; p < 4; ++p)
        tile[r + p * 8][c] = W[(size_t)(k0 + r + p * 8) * N + n0 + c];
    __syncthreads();
    #pragma unroll
    for (int p = 0; p < 4; ++p)
        Wt[(size_t)(n0 + r + p * 8) * K + k0 + c] = f2bf(tile[c][r + p * 8]);
}

// ---------------------------------------------------------------------------
// bf16 MFMA GEMM, 128x128 tile, 4 waves (2x2), BK=32, 3-stage LDS pipeline
// (48 KB), counted vmcnt(4), ONE top barrier per iter. setprio around MFMA.
// ---------------------------------------------------------------------------
__global__ __launch_bounds__(256, 3) void gemm_mfma(
    const unsigned short* __restrict__ A, const unsigned short* __restrict__ Bt,
    const float* __restrict__ bias, void* __restrict__ C,
    int M, int N, int K, int out_bf16)
{
    __shared__ __align__(16) char lds[49152];   // 3 stages x (A 8K | B 8K)
    int t = threadIdx.x;
    int wave = t >> 6, lane = t & 63;
    int lm = lane & 15, lkg = lane >> 4;
    int wr = wave >> 1, wc = wave & 1;

    // bijective XCD remap (m204)
    int gx = gridDim.x;
    int nwg = gx * gridDim.y;
    int lin = blockIdx.y * gx + blockIdx.x;
    int qq = nwg >> 3, rr = nwg & 7;
    int xcd = lin & 7, idx = lin >> 3;
    int newlin = (xcd < rr ? xcd * (qq + 1) : rr * (qq + 1) + (xcd - rr) * qq) + idx;
    int m0 = (newlin / gx) * 128, n0 = (newlin % gx) * 128;

    // staging roles: 2 chunks per matrix per thread, pre-swizzled source
    const unsigned short *gpa0, *gpa1, *gpb0, *gpb1;
    int la0, la1, lb0, lb1;
    {
        int o0 = t * 16, o1 = 4096 + t * 16;
        int r0 = o0 >> 6, s0 = ((o0 >> 4) & 3) ^ ((r0 >> 1) & 3);
        int r1 = o1 >> 6, s1 = ((o1 >> 4) & 3) ^ ((r1 >> 1) & 3);
        int ar0 = m0 + r0; if (ar0 >= M) ar0 = M - 1;
        int ar1 = m0 + r1; if (ar1 >= M) ar1 = M - 1;
        gpa0 = A + (size_t)ar0 * K + s0 * 8;  la0 = o0;
        gpa1 = A + (size_t)ar1 * K + s1 * 8;  la1 = o1;
        gpb0 = Bt + (size_t)(n0 + r0) * K + s0 * 8;  lb0 = 8192 + o0;
        gpb1 = Bt + (size_t)(n0 + r1) * K + s1 * 8;  lb1 = 8192 + o1;
    }

    f32x4 acc[4][4] = {};
    const int nt = K >> 5;      // 24

    // prologue: stage tiles 0 (buf0) and 1 (buf1); 8 loads stay in flight
    gl16(gpa0, &lds[la0]); gl16(gpa1, &lds[la1]);
    gl16(gpb0, &lds[lb0]); gl16(gpb1, &lds[lb1]);
    gpa0 += 32; gpa1 += 32; gpb0 += 32; gpb1 += 32;
    gl16(gpa0, &lds[16384 + la0]); gl16(gpa1, &lds[16384 + la1]);
    gl16(gpb0, &lds[16384 + lb0]); gl16(gpb1, &lds[16384 + lb1]);
    gpa0 += 32; gpa1 += 32; gpb0 += 32; gpb1 += 32;

    int cur = 0;
    for (int tt = 0; tt < nt; ++tt) {
        if (tt + 1 < nt) asm volatile("s_waitcnt vmcnt(4)" ::: "memory");
        else             asm volatile("s_waitcnt vmcnt(0)" ::: "memory");
        __builtin_amdgcn_s_barrier();   // tile tt fully in LDS (all waves)

        // stage tile tt+2 -> buf[(cur+2)%3] (its readers retired at tt-1)
        if (tt + 2 < nt) {
            int nx = cur + 2; if (nx >= 3) nx -= 3;
            char* nb = &lds[nx << 14];
            gl16(gpa0, nb + la0); gl16(gpa1, nb + la1);
            gl16(gpb0, nb + lb0); gl16(gpb1, nb + lb1);
            gpa0 += 32; gpa1 += 32; gpb0 += 32; gpb1 += 32;
        }

        char* base = &lds[cur << 14];
        bf16x8 af[4], bfr[4];
        #pragma unroll
        for (int m = 0; m < 4; ++m) {
            int row = wr * 64 + m * 16 + lm;
            af[m] = *reinterpret_cast<const bf16x8*>(
                base + row * 64 + ((lkg ^ ((row >> 1) & 3)) << 4));
        }
        #pragma unroll
        for (int n = 0; n < 4; ++n) {
            int row = wc * 64 + n * 16 + lm;
            bfr[n] = *reinterpret_cast<const bf16x8*>(
                base + 8192 + row * 64 + ((lkg ^ ((row >> 1) & 3)) << 4));
        }
        __builtin_amdgcn_s_setprio(1);
        #pragma unroll
        for (int m = 0; m < 4; ++m)
            #pragma unroll
            for (int n = 0; n < 4; ++n)
                acc[m][n] = __builtin_amdgcn_mfma_f32_16x16x32_bf16(
                    af[m], bfr[n], acc[m][n], 0, 0, 0);
        __builtin_amdgcn_s_setprio(0);

        cur = (cur == 2) ? 0 : cur + 1;
    }

    // epilogue: row-contiguous store order (n innermost => full 128B lines)
    float bv[4];
    #pragma unroll
    for (int n = 0; n < 4; ++n)
        bv[n] = bias ? bias[n0 + wc * 64 + n * 16 + lm] : 0.f;
    #pragma unroll
    for (int m = 0; m < 4; ++m) {
        #pragma unroll
        for (int r = 0; r < 4; ++r) {
            int row = m0 + wr * 64 + m * 16 + lkg * 4 + r;
            if (row >= M) continue;
            #pragma unroll
            for (int n = 0; n < 4; ++n) {
                int col = n0 + wc * 64 + n * 16 + lm;
                float o = acc[m][n][r] + bv[n];
                if (out_bf16)
                    ((unsigned short*)C)[(size_t)row * N + col] = f2bf(o);
                else
                    ((float*)C)[(size_t)row * N + col] = o;
            }
        }
    }
}

// ---------------------------------------------------------------------------
// Row-tiled depthwise 3x3 pool + LayerNorm (shared body).
// mode 3: q-ext [bh][pos][128] (q*QSCALE, ext zeros, [120]=PADSUP)
// mode 1: k-ext [bh][pos][128] (k, onehot(kh)/onehot(kw))
// mode 2: v^T   [bh][64][NKEYPAD]
// ---------------------------------------------------------------------------
__device__ __forceinline__ void pool_body(
    const unsigned short* src, const float* w, const float* g,
    const float* beta, unsigned short* outp, int bh, int orow,
    int stride, int OW, int mode, unsigned short* ibuf,
    int t, int wave, int lane)
{
    for (int i = t; i < 3 * 56 * 32; i += 256) {
        int pair = i >> 5, off = i & 31;
        int r = pair / 56, iw = pair % 56;
        int ih = orow * stride + r - 1;
        unsigned v = 0;
        if (ih >= 0 && ih < QH)
            v = *reinterpret_cast<const unsigned*>(
                src + (size_t)(1 + ih * QW + iw) * THREE_DIM + off * 2);
        *reinterpret_cast<unsigned*>(&ibuf[pair * 64 + off * 2]) = v;
    }

    float wreg[9];
    #pragma unroll
    for (int k = 0; k < 9; ++k) wreg[k] = w[lane * 9 + k];
    float gl = g[lane], bl = beta[lane];
    __syncthreads();

    int ntask = OW + ((orow == 0) ? 1 : 0);    // extra task: cls (pos 0)
    for (int task = wave; task < ntask; task += 4) {
        float val;
        int pos;
        if (task == OW) {                      // cls token
            val = bf2f(src[lane]);
            pos = 0;
        } else {
            int ow = task;
            float acc = 0.f;
            #pragma unroll
            for (int r = 0; r < 3; ++r) {
                #pragma unroll
                for (int c = 0; c < 3; ++c) {
                    int iwc = ow * stride + c - 1;
                    if (iwc < 0 || iwc >= QW) continue;
                    acc += bf2f(ibuf[(r * 56 + iwc) * 64 + lane]) * wreg[r * 3 + c];
                }
            }
            val = acc;
            pos = 1 + orow * OW + ow;
        }

        float mu = val;
        #pragma unroll
        for (int off = 32; off > 0; off >>= 1) mu += __shfl_xor(mu, off, 64);
        mu *= (1.f / 64.f);
        float dv = val - mu;
        float var = dv * dv;
        #pragma unroll
        for (int off = 32; off > 0; off >>= 1) var += __shfl_xor(var, off, 64);
        var *= (1.f / 64.f);
        float o = dv * rsqrtf(var + 1e-5f) * gl + bl;

        if (mode == 3) {
            unsigned short* row = outp + ((size_t)bh * NTOK + pos) * XD;
            row[lane] = f2bf(o * QSCALE);
            row[64 + lane] = (lane == 56) ? f2bf(PADSUP) : 0;
        } else if (mode == 1) {
            unsigned short* row = outp + ((size_t)bh * NKEYPAD + pos) * XD;
            row[lane] = f2bf(o);
            unsigned short ext = 0;
            if (pos > 0) {
                int kh = (pos - 1) / 28, kw = (pos - 1) % 28;
                if ((lane < 28 && lane == kh) ||
                    (lane >= 28 && lane < 56 && lane - 28 == kw))
                    ext = 0x3F80;   // 1.0 bf16
            }
            row[64 + lane] = ext;
        } else {
            outp[((size_t)bh * HD + lane) * NKEYPAD + pos] = f2bf(o);
        }
    }
}

__global__ __launch_bounds__(256) void pool_ln_q(
    const unsigned short* __restrict__ qkvb, const float* __restrict__ w,
    const float* __restrict__ g, const float* __restrict__ beta,
    unsigned short* __restrict__ outp)
{
    __shared__ unsigned short ibuf[3 * 56 * 64];
    int bid = blockIdx.x;
    int orow = bid % QH;
    int bh = bid / QH;
    int head = bh % NHEAD, b = bh / NHEAD;
    const unsigned short* src =
        qkvb + (size_t)b * NTOK * THREE_DIM + (size_t)head * HD;
    pool_body(src, w, g, beta, outp, bh, orow, 1, QW, 3, ibuf,
              threadIdx.x, threadIdx.x >> 6, threadIdx.x & 63);
}

// k (y=0) and v (y=1) pools in one launch; orow==27 blocks also write the
// pad rows (785..799): k-ext = pad-flag onehot, v^T pad cols = 0.
__global__ __launch_bounds__(256) void pool_ln_kv(
    const unsigned short* __restrict__ qkvb,
    const float* __restrict__ wk, const float* __restrict__ gk,
    const float* __restrict__ bk, unsigned short* __restrict__ kpx,
    const float* __restrict__ wv, const float* __restrict__ gv,
    const float* __restrict__ bv, unsigned short* __restrict__ vt16)
{
    __shared__ unsigned short ibuf[3 * 56 * 64];
    int bid = blockIdx.x;
    int orow = bid % 28;
    int bh = bid / 28;
    int head = bh % NHEAD, b = bh / NHEAD;
    int isv = blockIdx.y;
    int t = threadIdx.x;
    const unsigned short* src = qkvb + (size_t)b * NTOK * THREE_DIM
        + (size_t)(isv ? 2 : 1) * DIM + (size_t)head * HD;
    if (isv)
        pool_body(src, wv, gv, bv, vt16, bh, orow, 2, 28, 2, ibuf,
                  t, t >> 6, t & 63);
    else
        pool_body(src, wk, gk, bk, kpx, bh, orow, 2, 28, 1, ibuf,
                  t, t >> 6, t & 63);

    if (orow == 27) {               // fused pad work (was pad_kv kernel)
        if (isv) {
            for (int i = t; i < 64 * (NKEYPAD - NKEY); i += 256) {
                int d = i / (NKEYPAD - NKEY);
                int pos = NKEY + i % (NKEYPAD - NKEY);
                vt16[((size_t)bh * HD + d) * NKEYPAD + pos] = 0;
            }
        } else {
            for (int i = t; i < (NKEYPAD - NKEY) * XD; i += 256) {
                int pos = NKEY + i / XD, c = i % XD;
                kpx[((size_t)bh * NKEYPAD + pos) * XD + c] =
                    (c == 120) ? (unsigned short)0x3F80 : (unsigned short)0;
            }
        }
    }
}

// ---------------------------------------------------------------------------
// MFMA rel-pos dots -> bf16 Q-ext columns of qpx. blockIdx.z = mode.
// ---------------------------------------------------------------------------
__global__ __launch_bounds__(256) void rel_mfma(
    const unsigned short* __restrict__ qpx, const unsigned short* __restrict__ rh,
    const unsigned short* __restrict__ rw, unsigned short* __restrict__ qpx_out)
{
    __shared__ char bbuf[4096];     // [32 rows][64 bf16], XOR-swizzled
    int X = blockIdx.x;
    int m0 = blockIdx.y * 256;
    int mode = blockIdx.z;
    const unsigned short* rtab = mode ? rw : rh;
    int t = threadIdx.x;
    int wave = t >> 6, lane = t & 63;
    int lm = lane & 15, lkg = lane >> 4;

    {
        int row = t >> 3, c8 = t & 7;
        int4 val = {0, 0, 0, 0};
        if (row < 28) {
            int dh = X - 2 * row + 54;              // in [0, 110)
            val = *reinterpret_cast<const int4*>(rtab + (size_t)dh * HD + c8 * 8);
        }
        *reinterpret_cast<int4*>(&bbuf[row * 128 + ((c8 * 16) ^ ((row & 7) << 4))]) = val;
    }
    __syncthreads();

    int rbase = m0 + wave * 64 + lm;
    f32x4 acc[4][2] = {};
    #pragma unroll
    for (int kc = 0; kc < 2; ++kc) {
        bf16x8 bfrag[2];
        #pragma unroll
        for (int nb = 0; nb < 2; ++nb) {
            int row = nb * 16 + lm;
            bfrag[nb] = *reinterpret_cast<const bf16x8*>(
                &bbuf[row * 128 + (((kc * 4 + lkg) * 16) ^ ((row & 7) << 4))]);
        }
        #pragma unroll
        for (int m = 0; m < 4; ++m) {
            int rho = rbase + m * 16; if (rho > RELROWS - 1) rho = RELROWS - 1;
            int bh = rho / 56, rem = rho % 56;
            int pos1 = (mode == 0) ? X * 56 + rem : rem * 56 + X;
            const unsigned short* qsrc =
                qpx + ((size_t)bh * NTOK + 1 + pos1) * XD + kc * 32 + lkg * 8;
            bf16x8 af = *reinterpret_cast<const bf16x8*>(qsrc);
            acc[m][0] = __builtin_amdgcn_mfma_f32_16x16x32_bf16(af, bfrag[0], acc[m][0], 0, 0, 0);
            acc[m][1] = __builtin_amdgcn_mfma_f32_16x16x32_bf16(af, bfrag[1], acc[m][1], 0, 0, 0);
        }
    }

    #pragma unroll
    for (int m = 0; m < 4; ++m) {
        #pragma unroll
        for (int r = 0; r < 4; ++r) {
            int rho = m0 + wave * 64 + m * 16 + lkg * 4 + r;
            if (rho >= RELROWS) continue;
            int bh = rho / 56, rem = rho % 56;
            int pos1 = (mode == 0) ? X * 56 + rem : rem * 56 + X;
            unsigned short* dst =
                qpx_out + ((size_t)bh * NTOK + 1 + pos1) * XD + 64 + mode * 28;
            dst[lm] = f2bf(acc[m][0][r] * 8.f);             // -> log2e * (q.r)
            if (lm < 12) dst[16 + lm] = f2bf(acc[m][1][r] * 8.f);
        }
    }
}

// ---------------------------------------------------------------------------
// MFMA flash attention, 4 waves x 32 q-rows (QT=128, 256 thr), swapped QK
// (mfma(K,Q): lane holds q=lm, keys lkg*4+r), bias in ext-128 K-dim,
// 2-STAGE pipeline (32 KB LDS). Stage for jt+1 issued AFTER the barrier
// (2-buffer WAR safety), lands during this iteration's compute.
// XCD swizzle, exp2 scores, b64 P-writes, lane-linear P-read, lkg-group
// reduced softmax denominators. [Empirical optimum of explored space.]
// ---------------------------------------------------------------------------
__global__ __launch_bounds__(256, 3) void attn_mfma(
    const unsigned short* __restrict__ qpx, const unsigned short* __restrict__ kpx,
    const unsigned short* __restrict__ vt, unsigned short* __restrict__ outp)
{
    __shared__ __align__(16) char kbuf[2][8192];   // Kext tile [32][128] bf16
    __shared__ __align__(16) char vbuf[2][4096];   // Vt tile  [64][32]  bf16
    __shared__ __align__(16) char pbuf[4][2048];   // per-wave P [32 q][32 k]

    int bid0 = blockIdx.x;
    int bid = (bid0 & 7) * ((NBH * NQT2) / 8) + (bid0 >> 3);   // 1200 % 8 == 0
    int tile = bid % NQT2;
    int bh = bid / NQT2;
    int head = bh % NHEAD, b = bh / NHEAD;
    int q0 = tile * QT2;
    int t = threadIdx.x;
    int wave = t >> 6, lane = t & 63;
    int lm = lane & 15, lkg = lane >> 4;

    const unsigned short* kb  = kpx + (size_t)bh * NKEYPAD * XD;
    const unsigned short* vtb = vt + (size_t)bh * HD * NKEYPAD;

    // Q fragments: 2 row-blocks x 4 chunks of 32 ext-dims
    bf16x8 qf[2][4] = {};
    #pragma unroll
    for (int rb = 0; rb < 2; ++rb) {
        int qrow = q0 + wave * 32 + rb * 16 + lm;
        if (qrow < NTOK) {
            const unsigned short* qs = qpx + ((size_t)bh * NTOK + qrow) * XD + lkg * 8;
            qf[rb][0] = *reinterpret_cast<const bf16x8*>(qs);
            qf[rb][1] = *reinterpret_cast<const bf16x8*>(qs + 32);
            qf[rb][2] = *reinterpret_cast<const bf16x8*>(qs + 64);
            qf[rb][3] = *reinterpret_cast<const bf16x8*>(qs + 96);
        }
    }

    f32x4 oacc[2][4] = {};
    float osum[2] = {0.f, 0.f};    // partial per lane: q = lm, keys of lkg grp

    // K staging: 2 chunks/thread (rows 0-15, 16-31), pre-swizzled source
    int kr = t >> 4;
    int ks = (t & 15) ^ (kr & 7);
    const unsigned short* kp0 = kb + (size_t)kr * XD + ks * 8;
    const unsigned short* kp1 = kb + (size_t)(kr + 16) * XD + ks * 8;
    int kd0 = t * 16, kd1 = 4096 + t * 16;
    // V staging: 1 chunk/thread
    int vr = t >> 2;
    int vs = (t & 3) ^ ((vr >> 1) & 3);
    const unsigned short* vp0 = vtb + (size_t)vr * NKEYPAD + vs * 8;
    int vd = t * 16;

    const int NT = NKEYPAD / 32;   // 25

    // prologue: stage tile 0 into buf 0 (3 loads)
    gl16(kp0, &kbuf[0][kd0]); gl16(kp1, &kbuf[0][kd1]); gl16(vp0, &vbuf[0][vd]);
    kp0 += 32 * XD; kp1 += 32 * XD; vp0 += 32;

    // P write address base: byte(P[q][k]) = (k>>3)*256 + q*16 + (k&7)*2
    int pwbase = lm * 16 + ((lkg & 1) << 3);   // + (nb*2 + (lkg>>1))*256 + rb*1024

    int cur = 0;
    for (int jt = 0; jt < NT; ++jt) {
        // only tile jt's 3 loads are outstanding; they had the whole
        // previous compute phase to land.
        asm volatile("s_waitcnt vmcnt(0)" ::: "memory");
        __builtin_amdgcn_s_barrier();   // tile jt in LDS; prev reads retired

        // stage tile jt+1 into buf[cur^1] (WAR-safe: post-barrier);
        // overlaps this iteration's compute.
        if (jt + 1 < NT) {
            gl16(kp0, &kbuf[cur ^ 1][kd0]);
            gl16(kp1, &kbuf[cur ^ 1][kd1]);
            gl16(vp0, &vbuf[cur ^ 1][vd]);
            kp0 += 32 * XD; kp1 += 32 * XD; vp0 += 32;
        }

        // Swapped QK^T: S[k][q] = mfma(Kext, Qext); kf shared across both rb
        f32x4 a00 = {0.f,0.f,0.f,0.f}, a01 = {0.f,0.f,0.f,0.f};
        f32x4 a10 = {0.f,0.f,0.f,0.f}, a11 = {0.f,0.f,0.f,0.f};
        __builtin_amdgcn_s_setprio(1);
        #pragma unroll
        for (int kc = 0; kc < 4; ++kc) {
            int sl = (kc * 4 + lkg) ^ (lm & 7);
            bf16x8 kf0 = *reinterpret_cast<const bf16x8*>(&kbuf[cur][lm * 256 + sl * 16]);
            bf16x8 kf1 = *reinterpret_cast<const bf16x8*>(&kbuf[cur][(16 + lm) * 256 + sl * 16]);
            a00 = __builtin_amdgcn_mfma_f32_16x16x32_bf16(kf0, qf[0][kc], a00, 0, 0, 0);
            a01 = __builtin_amdgcn_mfma_f32_16x16x32_bf16(kf1, qf[0][kc], a01, 0, 0, 0);
            a10 = __builtin_amdgcn_mfma_f32_16x16x32_bf16(kf0, qf[1][kc], a10, 0, 0, 0);
            a11 = __builtin_amdgcn_mfma_f32_16x16x32_bf16(kf1, qf[1][kc], a11, 0, 0, 0);
        }
        __builtin_amdgcn_s_setprio(0);

        // exp2 + pack pairs + b64 write (4 consecutive k per write)
        #pragma unroll
        for (int rb = 0; rb < 2; ++rb) {
            #pragma unroll
            for (int nb = 0; nb < 2; ++nb) {
                f32x4 a = rb ? (nb ? a11 : a10) : (nb ? a01 : a00);
                float e0, e1, e2, e3;
                asm("v_exp_f32 %0, %1" : "=v"(e0) : "v"(a[0]));
                asm("v_exp_f32 %0, %1" : "=v"(e1) : "v"(a[1]));
                asm("v_exp_f32 %0, %1" : "=v"(e2) : "v"(a[2]));
                asm("v_exp_f32 %0, %1" : "=v"(e3) : "v"(a[3]));
                osum[rb] += (e0 + e1) + (e2 + e3);
                union { float f; unsigned u; } u0, u1, u2, u3;
                u0.f = e0; u1.f = e1; u2.f = e2; u3.f = e3;
                uint2 pk;
                pk.x = (u0.u >> 16) | (u1.u & 0xFFFF0000u);   // k+0, k+1
                pk.y = (u2.u >> 16) | (u3.u & 0xFFFF0000u);   // k+2, k+3
                int addr = (rb << 10) + ((nb * 2 + (lkg >> 1)) << 8) + pwbase;
                *reinterpret_cast<uint2*>(&pbuf[wave][addr]) = pk;
            }
        }

        // PV: O[rb] += P[rb][16x32] * Vt ; pf read is lane-linear (no conflict)
        bf16x8 pf0 = *reinterpret_cast<const bf16x8*>(&pbuf[wave][lane * 16]);
        bf16x8 pf1 = *reinterpret_cast<const bf16x8*>(&pbuf[wave][1024 + lane * 16]);
        __builtin_amdgcn_s_setprio(1);
        #pragma unroll
        for (int db = 0; db < 4; ++db) {
            int row = db * 16 + lm;
            bf16x8 vf = *reinterpret_cast<const bf16x8*>(
                &vbuf[cur][row * 64 + ((lkg ^ ((row >> 1) & 3)) << 4)]);
            oacc[0][db] = __builtin_amdgcn_mfma_f32_16x16x32_bf16(pf0, vf, oacc[0][db], 0, 0, 0);
            oacc[1][db] = __builtin_amdgcn_mfma_f32_16x16x32_bf16(pf1, vf, oacc[1][db], 0, 0, 0);
        }
        __builtin_amdgcn_s_setprio(0);

        cur ^= 1;
    }

    // FULL denominator: reduce partials across the 4 lkg groups (bits 4,5),
    // then lane-local reciprocal; broadcast to output layout via shfl.
    #pragma unroll
    for (int rb = 0; rb < 2; ++rb) {
        osum[rb] += __shfl_xor(osum[rb], 16, 64);
        osum[rb] += __shfl_xor(osum[rb], 32, 64);
    }
    float inv[2] = { 1.f / osum[0], 1.f / osum[1] };
    #pragma unroll
    for (int rb = 0; rb < 2; ++rb) {
        #pragma unroll
        for (int r = 0; r < 4; ++r) {
            float invq = __shfl(inv[rb], lkg * 4 + r, 64);   // lane with lm = q
            int qpos = q0 + wave * 32 + rb * 16 + lkg * 4 + r;
            if (qpos >= NTOK) continue;
            unsigned short* orow = outp + ((size_t)b * NTOK + qpos) * DIM + (size_t)head * HD;
            const unsigned short* qres = qpx + ((size_t)bh * NTOK + qpos) * XD;
            #pragma unroll
            for (int db = 0; db < 4; ++db) {
                int d = db * 16 + lm;
                float o = oacc[rb][db][r] * invq;
                if (qpos > 0) o += bf2f(qres[d]) * QUNSCALE;   // residual
                orow[d] = f2bf(o);
            }
        }
    }
}

// ---------------------------------------------------------------------------
extern "C" void kernel_launch(void* const* d_in, const int* in_sizes, int n_in,
                              void* d_out, int out_size, void* d_ws, size_t ws_size,
                              hipStream_t stream) {
    const float* x     = (const float*)d_in[0];
    const float* Wqkv  = (const float*)d_in[1];
    const float* pqw   = (const float*)d_in[2];
    const float* pkw   = (const float*)d_in[3];
    const float* pvw   = (const float*)d_in[4];
    const float* gq    = (const float*)d_in[5];
    const float* bq    = (const float*)d_in[6];
    const float* gk    = (const float*)d_in[7];
    const float* bk    = (const float*)d_in[8];
    const float* gv    = (const float*)d_in[9];
    const float* bv    = (const float*)d_in[10];
    const float* rph   = (const float*)d_in[11];
    const float* rpw   = (const float*)d_in[12];
    const float* Wproj = (const float*)d_in[13];
    const float* bproj = (const float*)d_in[14];

    unsigned short* qkvb  = (unsigned short*)d_ws;                 // [M][2304] bf16
    unsigned short* qpx   = qkvb + (size_t)MROWS * THREE_DIM;      // [48][3137][128]
    unsigned short* kpx   = qpx + (size_t)NBH * NTOK * XD;         // [48][800][128]
    unsigned short* vt16  = kpx + (size_t)NBH * NKEYPAD * XD;      // [48][64][800]
    unsigned short* xbf   = vt16 + (size_t)NBH * HD * NKEYPAD;     // [M][768]
    unsigned short* wqkvt = xbf + (size_t)MROWS * DIM;             // [2304][768]
    unsigned short* wprojt= wqkvt + (size_t)DIM * THREE_DIM;       // [768][768]
    unsigned short* rphb  = wprojt + (size_t)DIM * DIM;            // [111][64]
    unsigned short* rpwb  = rphb + 7104;
    unsigned short* attn_bf = qkvb;            // alias (qkvb dead after pools)

    dim3 blk(256);

    // 0) bf16 conversions (x; weights+rel tables in one launch)
    cvt_bf16<<<2048, blk, 0, stream>>>(x, xbf, (int)((size_t)MROWS * DIM / 4));
    {
        dim3 g(THREE_DIM / 32, DIM / 32, 3);
        transpose_cvt<<<g, blk, 0, stream>>>(Wqkv, wqkvt, Wproj, wprojt,
                                             rph, rpw, rphb, rpwb);
    }

    // 1) qkv = x @ Wqkv   (bf16 MFMA 128^2 pipelined, bf16 out)
    {
        dim3 grid(THREE_DIM / 128, (MROWS + 127) / 128);
        gemm_mfma<<<grid, blk, 0, stream>>>(xbf, wqkvt, nullptr, qkvb,
                                            MROWS, THREE_DIM, DIM, 1);
    }

    // 2) pool + LN: q-ext; k-ext + v^T merged (pad rows fused into orow==27)
    pool_ln_q<<<NBH * QH, blk, 0, stream>>>(qkvb, pqw, gq, bq, qpx);
    {
        dim3 g(NBH * 28, 2);
        pool_ln_kv<<<g, blk, 0, stream>>>(qkvb, pkw, gk, bk, kpx,
                                          pvw, gv, bv, vt16);
    }

    // 3) rel-pos dots -> Q-ext columns (bf16, in-place into qpx), both modes
    {
        dim3 g(56, (RELROWS + 255) / 256, 2);
        rel_mfma<<<g, blk, 0, stream>>>(qpx, rphb, rpwb, qpx);
    }

    // 4) MFMA flash attention (bias folded, exp2 scores, 2-stage/32KB)
    attn_mfma<<<NBH * NQT2, blk, 0, stream>>>(qpx, kpx, vt16, attn_bf);

    // 5) out = attn_out @ Wproj + bproj   (bf16 MFMA, fp32 out)
    {
        dim3 grid(DIM / 128, (MROWS + 127) / 128);
        gemm_mfma<<<grid, blk, 0, stream>>>(attn_bf, wprojt, bproj, d_out,
                                            MROWS, DIM, DIM, 0);
    }
}